// Round 2
// baseline (662.132 us; speedup 1.0000x reference)
//
#include <hip/hip_runtime.h>
#include <stdint.h>

// ============================================================================
// LUKE entity-aware attention block, MI355X gfx950, round 1.
// I/O dtype is FP32 (reference is jnp.float32). Internal compute: bf16 MFMA
// with fp32 accumulation. Ingest kernels cast fp32->bf16.
// ws usage ~175 MB (ASSUMPTION: ws_size >= that).
// ============================================================================

#define B_ 16
#define S_ 512
#define E_ 128
#define T_ 640
#define D_ 768
#define H_ 12
#define DH_ 64
#define FF_ 3072

typedef unsigned short u16;
typedef __bf16 bf16x8 __attribute__((ext_vector_type(8)));
typedef u16 u16x8 __attribute__((ext_vector_type(8)));
typedef float f32x4 __attribute__((ext_vector_type(4)));

__device__ __forceinline__ float b2f(u16 v) {
  unsigned u = ((unsigned)v) << 16;
  return __builtin_bit_cast(float, u);
}
__device__ __forceinline__ u16 f2b(float f) {  // RNE
  unsigned u = __builtin_bit_cast(unsigned, f);
  u += 0x7FFFu + ((u >> 16) & 1u);
  return (u16)(u >> 16);
}

// async global->LDS, 16B per lane (wave-uniform base + lane*16 — m97 pattern)
__device__ __forceinline__ void gl_lds16(const u16* g, u16* l) {
  __builtin_amdgcn_global_load_lds((__attribute__((address_space(1))) const void*)g,
                                   (__attribute__((address_space(3))) void*)l, 16, 0, 0);
}

// ============================================================================
// GEMM: C[M,N] = A[M,K] @ Bt[N,K]^T (+bias[N]), bf16 in, fp32 accum, bf16 out.
// 128x128 tile, BK=32, 4 waves (2x2 of 64x64), mfma_f32_16x16x32_bf16.
// EPI: 0 = bias ; 1 = bias + exact GELU
// ============================================================================
template <int EPI>
__global__ __launch_bounds__(256) void gemm_kernel(
    const u16* __restrict__ A, const u16* __restrict__ Bt,
    const u16* __restrict__ bias, u16* __restrict__ C,
    int lda, int ldc, int K, long long sA, long long sC) {
  __shared__ __align__(16) u16 As[128 * 32];
  __shared__ __align__(16) u16 Bs[128 * 32];

  const int tid = threadIdx.x;
  const int m0 = blockIdx.x * 128, n0 = blockIdx.y * 128;
  A += (long long)blockIdx.z * sA + (long long)m0 * lda;
  Bt += (long long)n0 * K;
  C += (long long)blockIdx.z * sC;

  const int lane = tid & 63, wave = tid >> 6;
  const int wm = (wave & 1) << 6, wn = (wave >> 1) << 6;
  const int l15 = lane & 15, quad = lane >> 4;

  const int r0 = tid >> 2, c0 = (tid & 3) << 3;
  const u16* ga0 = A + (long long)r0 * lda + c0;
  const u16* ga1 = A + (long long)(r0 + 64) * lda + c0;
  const u16* gb0 = Bt + (long long)r0 * K + c0;
  const u16* gb1 = Bt + (long long)(r0 + 64) * K + c0;

  f32x4 acc[4][4] = {};

  for (int k0 = 0; k0 < K; k0 += 32) {
    __syncthreads();
    gl_lds16(ga0 + k0, &As[tid * 8]);
    gl_lds16(ga1 + k0, &As[2048 + tid * 8]);
    gl_lds16(gb0 + k0, &Bs[tid * 8]);
    gl_lds16(gb1 + k0, &Bs[2048 + tid * 8]);
    __syncthreads();

    bf16x8 af[4], bfr[4];
#pragma unroll
    for (int i = 0; i < 4; i++)
      af[i] = *(const bf16x8*)&As[(wm + i * 16 + l15) * 32 + quad * 8];
#pragma unroll
    for (int i = 0; i < 4; i++)
      bfr[i] = *(const bf16x8*)&Bs[(wn + i * 16 + l15) * 32 + quad * 8];
#pragma unroll
    for (int i = 0; i < 4; i++)
#pragma unroll
      for (int j = 0; j < 4; j++)
        acc[i][j] = __builtin_amdgcn_mfma_f32_16x16x32_bf16(af[i], bfr[j], acc[i][j], 0, 0, 0);
  }

  float bv[4];
#pragma unroll
  for (int j = 0; j < 4; j++) bv[j] = b2f(bias[n0 + wn + j * 16 + l15]);
#pragma unroll
  for (int i = 0; i < 4; i++) {
    const int row = m0 + wm + i * 16 + quad * 4;
#pragma unroll
    for (int j = 0; j < 4; j++) {
      const int col = n0 + wn + j * 16 + l15;
#pragma unroll
      for (int r = 0; r < 4; r++) {
        float v = acc[i][j][r] + bv[j];
        if (EPI == 1) v = 0.5f * v * (1.0f + erff(v * 0.70710678118654752f));
        C[(long long)(row + r) * ldc + col] = f2b(v);
      }
    }
  }
}

// ============================================================================
// Fused attention: block = (b, h, 16-query tile). Scores in LDS bf16 (in-place
// exp), softmax normalization deferred to PV epilogue. Word keys (<512) use
// Qw, entity keys use Qe. Mask is fp32.
// ============================================================================
__global__ __launch_bounds__(256) void attn_kernel(
    const u16* __restrict__ Qw, const u16* __restrict__ Qe,
    const u16* __restrict__ Kb, const u16* __restrict__ Vb,
    const float* __restrict__ mask, u16* __restrict__ ctx) {
  const int q0 = blockIdx.x * 16;
  const int h = blockIdx.y;
  const int b = blockIdx.z;

  __shared__ __align__(16) u16 scp[16 * 648];
  __shared__ __align__(16) u16 vt[64 * 72];
  __shared__ float rsum[16];

  const int tid = threadIdx.x;
  const int lane = tid & 63, wave = tid >> 6;
  const int l15 = lane & 15, quad = lane >> 4;

  const long long bh = (long long)b * T_ * D_ + h * DH_;

  const u16* qwp = Qw + bh + (long long)(q0 + l15) * D_ + quad * 8;
  const u16* qep = Qe + bh + (long long)(q0 + l15) * D_ + quad * 8;
  const bf16x8 qwf0 = *(const bf16x8*)(qwp);
  const bf16x8 qwf1 = *(const bf16x8*)(qwp + 32);
  const bf16x8 qef0 = *(const bf16x8*)(qep);
  const bf16x8 qef1 = *(const bf16x8*)(qep + 32);

  for (int i = 0; i < 10; i++) {
    const int key0 = wave * 160 + i * 16;  // wave-uniform, 16-aligned
    const u16* kp = Kb + bh + (long long)(key0 + l15) * D_ + quad * 8;
    const bf16x8 kf0 = *(const bf16x8*)(kp);
    const bf16x8 kf1 = *(const bf16x8*)(kp + 32);
    bf16x8 qf0, qf1;
    if (key0 < S_) { qf0 = qwf0; qf1 = qwf1; } else { qf0 = qef0; qf1 = qef1; }
    f32x4 a = {0.f, 0.f, 0.f, 0.f};
    a = __builtin_amdgcn_mfma_f32_16x16x32_bf16(qf0, kf0, a, 0, 0, 0);
    a = __builtin_amdgcn_mfma_f32_16x16x32_bf16(qf1, kf1, a, 0, 0, 0);
    const float mv = mask[b * T_ + key0 + l15];
#pragma unroll
    for (int r = 0; r < 4; r++)
      scp[(quad * 4 + r) * 648 + key0 + l15] = f2b(a[r] * 0.125f + mv);
  }
  __syncthreads();

  {
    const int srow = tid >> 4, ssub = tid & 15;
    float mx = -1e30f;
#pragma unroll
    for (int c = 0; c < 40; c++) mx = fmaxf(mx, b2f(scp[srow * 648 + ssub + c * 16]));
#pragma unroll
    for (int d = 8; d; d >>= 1) mx = fmaxf(mx, __shfl_xor(mx, d, 16));
    float sum = 0.f;
#pragma unroll
    for (int c = 0; c < 40; c++) {
      const int idx = srow * 648 + ssub + c * 16;
      const float e = __expf(b2f(scp[idx]) - mx);
      sum += e;
      scp[idx] = f2b(e);
    }
#pragma unroll
    for (int d = 8; d; d >>= 1) sum += __shfl_xor(sum, d, 16);
    if (ssub == 0) rsum[srow] = sum;
  }

  f32x4 o = {0.f, 0.f, 0.f, 0.f};
  const int vkey = tid & 63;
  for (int kc = 0; kc < T_; kc += 64) {
    __syncthreads();
    const u16* vp = Vb + bh + (long long)(kc + vkey) * D_ + wave * 16;
    const u16x8 v0 = *(const u16x8*)(vp);
    const u16x8 v1 = *(const u16x8*)(vp + 8);
#pragma unroll
    for (int e = 0; e < 8; e++) vt[(wave * 16 + e) * 72 + vkey] = v0[e];
#pragma unroll
    for (int e = 0; e < 8; e++) vt[(wave * 16 + 8 + e) * 72 + vkey] = v1[e];
    __syncthreads();
#pragma unroll
    for (int ks = 0; ks < 2; ks++) {
      const bf16x8 pf = *(const bf16x8*)&scp[l15 * 648 + kc + ks * 32 + quad * 8];
      const bf16x8 vf = *(const bf16x8*)&vt[(wave * 16 + l15) * 72 + ks * 32 + quad * 8];
      o = __builtin_amdgcn_mfma_f32_16x16x32_bf16(pf, vf, o, 0, 0, 0);
    }
  }

  u16* cp = ctx + bh + (long long)(q0 + quad * 4) * D_ + wave * 16 + l15;
#pragma unroll
  for (int r = 0; r < 4; r++) cp[(long long)r * D_] = f2b(o[r] / rsum[quad * 4 + r]);
}

// ============================================================================
// LayerNorm over D=768 with fused residual add. SPLIT=1: scatter rows into
// [word | entity] fp32 output (d_out). SPLIT=0: bf16 out.
// ============================================================================
template <int SPLIT>
__global__ __launch_bounds__(256) void ln_kernel(
    const u16* __restrict__ x, const u16* __restrict__ res,
    const u16* __restrict__ g, const u16* __restrict__ beta,
    void* __restrict__ out_) {
  const int row = blockIdx.x;
  const int tid = threadIdx.x;
  const u16* xp = x + (long long)row * D_;
  const u16* rp = res + (long long)row * D_;
  float v[3], s = 0.f, s2 = 0.f;
#pragma unroll
  for (int i = 0; i < 3; i++) {
    const int c = tid + i * 256;
    v[i] = b2f(xp[c]) + b2f(rp[c]);
    s += v[i];
    s2 += v[i] * v[i];
  }
#pragma unroll
  for (int d = 32; d; d >>= 1) {
    s += __shfl_xor(s, d, 64);
    s2 += __shfl_xor(s2, d, 64);
  }
  __shared__ float red[8];
  const int wave = tid >> 6;
  if ((tid & 63) == 0) { red[wave * 2] = s; red[wave * 2 + 1] = s2; }
  __syncthreads();
  s = red[0] + red[2] + red[4] + red[6];
  s2 = red[1] + red[3] + red[5] + red[7];
  const float mean = s * (1.f / 768.f);
  const float var = s2 * (1.f / 768.f) - mean * mean;
  const float rs = rsqrtf(var + 1e-12f);
  if (SPLIT) {
    float* out = (float*)out_;
    const int b = row / T_, t = row % T_;
    float* op = (t < S_) ? out + ((long long)b * S_ + t) * D_
                         : out + (long long)B_ * S_ * D_ + ((long long)b * E_ + (t - S_)) * D_;
#pragma unroll
    for (int i = 0; i < 3; i++) {
      const int c = tid + i * 256;
      op[c] = (v[i] - mean) * rs * b2f(g[c]) + b2f(beta[c]);
    }
  } else {
    u16* op = (u16*)out_ + (long long)row * D_;
#pragma unroll
    for (int i = 0; i < 3; i++) {
      const int c = tid + i * 256;
      op[c] = f2b((v[i] - mean) * rs * b2f(g[c]) + b2f(beta[c]));
    }
  }
}

// out[N,K] = bf16( in[K,N]^T ), in fp32. tiled 32x32, block (32,8)
__global__ __launch_bounds__(256) void transpose_kernel(
    const float* __restrict__ in, u16* __restrict__ out, int K, int N) {
  __shared__ u16 t[32][33];
  const int n0 = blockIdx.x * 32, k0 = blockIdx.y * 32;
  const int tx = threadIdx.x, ty = threadIdx.y;
#pragma unroll
  for (int i = 0; i < 4; i++)
    t[ty + i * 8][tx] = f2b(in[(long long)(k0 + ty + i * 8) * N + n0 + tx]);
  __syncthreads();
#pragma unroll
  for (int i = 0; i < 4; i++)
    out[(long long)(n0 + ty + i * 8) * K + k0 + tx] = t[tx][ty + i * 8];
}

// xall[b,0:S]=word[b], xall[b,S:T]=entity[b]; fp32 in -> bf16 out
__global__ __launch_bounds__(256) void concat_kernel(
    const float* __restrict__ w, const float* __restrict__ e, u16* __restrict__ x) {
  const long long i = (long long)(blockIdx.x * 256 + threadIdx.x) * 8;
  const long long NW = (long long)B_ * S_ * D_;
  const long long NE = (long long)B_ * E_ * D_;
  const long long SD = (long long)S_ * D_;
  const long long ED = (long long)E_ * D_;
  const long long TD = (long long)T_ * D_;
  const float* src;
  u16* dst;
  if (i < NW) {
    const long long b = i / SD, r = i % SD;
    src = w + i;
    dst = &x[b * TD + r];
  } else {
    const long long j = i - NW;
    if (j >= NE) return;
    const long long b = j / ED, r = j % ED;
    src = e + j;
    dst = &x[b * TD + SD + r];
  }
  const float4 f0 = *(const float4*)(src);
  const float4 f1 = *(const float4*)(src + 4);
  u16x8 o;
  o[0] = f2b(f0.x); o[1] = f2b(f0.y); o[2] = f2b(f0.z); o[3] = f2b(f0.w);
  o[4] = f2b(f1.x); o[5] = f2b(f1.y); o[6] = f2b(f1.z); o[7] = f2b(f1.w);
  *(u16x8*)dst = o;
}

// 13 small fp32 vectors -> bf16
struct CvtArgs { const float* src[13]; u16* dst[13]; int n[13]; };
__global__ __launch_bounds__(256) void cvt_vecs_kernel(CvtArgs a) {
  const int v = blockIdx.x;
  const float* s = a.src[v];
  u16* d = a.dst[v];
  const int n = a.n[v];
  for (int i = threadIdx.x; i < n; i += 256) d[i] = f2b(s[i]);
}

extern "C" void kernel_launch(void* const* d_in, const int* in_sizes, int n_in,
                              void* d_out, int out_size, void* d_ws, size_t ws_size,
                              hipStream_t stream) {
  (void)in_sizes; (void)n_in; (void)out_size; (void)ws_size;
  const float* word = (const float*)d_in[0];
  const float* ent = (const float*)d_in[1];
  const float* mask = (const float*)d_in[2];
  const float* W_q = (const float*)d_in[3];
  const float* b_q = (const float*)d_in[4];
  const float* W_k = (const float*)d_in[5];
  const float* b_k = (const float*)d_in[6];
  const float* W_v = (const float*)d_in[7];
  const float* b_v = (const float*)d_in[8];
  const float* W_w2e = (const float*)d_in[9];
  const float* b_w2e = (const float*)d_in[10];
  const float* W_e2w = (const float*)d_in[11];
  const float* b_e2w = (const float*)d_in[12];
  const float* W_e2e = (const float*)d_in[13];
  const float* b_e2e = (const float*)d_in[14];
  const float* W_ao = (const float*)d_in[15];
  const float* b_ao = (const float*)d_in[16];
  const float* g_ao = (const float*)d_in[17];
  const float* be_ao = (const float*)d_in[18];
  const float* W_i = (const float*)d_in[19];
  const float* b_i = (const float*)d_in[20];
  const float* W_o = (const float*)d_in[21];
  const float* b_o = (const float*)d_in[22];
  const float* g_o = (const float*)d_in[23];
  const float* be_o = (const float*)d_in[24];

  const size_t DD = (size_t)D_ * D_ * 2;
  const size_t DFF = (size_t)D_ * FF_ * 2;
  const size_t TD = (size_t)B_ * T_ * D_ * 2;
  size_t off = 0;
  char* base = (char*)d_ws;
  auto take = [&](size_t n) { void* p = base + off; off += n; return p; };
  u16* wqT = (u16*)take(DD);
  u16* wkT = (u16*)take(DD);
  u16* wvT = (u16*)take(DD);
  u16* ww2eT = (u16*)take(DD);
  u16* we2wT = (u16*)take(DD);
  u16* we2eT = (u16*)take(DD);
  u16* waoT = (u16*)take(DD);
  u16* wiT = (u16*)take(DFF);
  u16* woT = (u16*)take(DFF);
  u16* vecs = (u16*)take(2 * 16384);
  u16* xall = (u16*)take(TD);
  u16* qw = (u16*)take(TD);
  u16* qe = (u16*)take(TD);
  u16* kb = (u16*)take(TD);
  u16* vb = (u16*)take(TD);
  u16* ctxb = (u16*)take(TD);
  u16* inter = (u16*)take((size_t)B_ * T_ * FF_ * 2);
  // bf16 bias/affine vectors
  u16* bq = vecs + 0 * 768;
  u16* bk = vecs + 1 * 768;
  u16* bv = vecs + 2 * 768;
  u16* bw2e = vecs + 3 * 768;
  u16* be2w = vecs + 4 * 768;
  u16* be2e = vecs + 5 * 768;
  u16* bao = vecs + 6 * 768;
  u16* gao = vecs + 7 * 768;
  u16* beao = vecs + 8 * 768;
  u16* bo = vecs + 9 * 768;
  u16* go = vecs + 10 * 768;
  u16* beo = vecs + 11 * 768;
  u16* bi = vecs + 12 * 768;  // 3072 elems
  // buffer reuse after attention:
  u16* ao_raw = qw;
  u16* ao = kb;
  u16* out_raw = qe;

  CvtArgs ca;
  ca.src[0] = b_q;   ca.dst[0] = bq;   ca.n[0] = 768;
  ca.src[1] = b_k;   ca.dst[1] = bk;   ca.n[1] = 768;
  ca.src[2] = b_v;   ca.dst[2] = bv;   ca.n[2] = 768;
  ca.src[3] = b_w2e; ca.dst[3] = bw2e; ca.n[3] = 768;
  ca.src[4] = b_e2w; ca.dst[4] = be2w; ca.n[4] = 768;
  ca.src[5] = b_e2e; ca.dst[5] = be2e; ca.n[5] = 768;
  ca.src[6] = b_ao;  ca.dst[6] = bao;  ca.n[6] = 768;
  ca.src[7] = g_ao;  ca.dst[7] = gao;  ca.n[7] = 768;
  ca.src[8] = be_ao; ca.dst[8] = beao; ca.n[8] = 768;
  ca.src[9] = b_o;   ca.dst[9] = bo;   ca.n[9] = 768;
  ca.src[10] = g_o;  ca.dst[10] = go;  ca.n[10] = 768;
  ca.src[11] = be_o; ca.dst[11] = beo; ca.n[11] = 768;
  ca.src[12] = b_i;  ca.dst[12] = bi;  ca.n[12] = 3072;
  cvt_vecs_kernel<<<13, 256, 0, stream>>>(ca);

  const dim3 tb(32, 8);
  transpose_kernel<<<dim3(24, 24), tb, 0, stream>>>(W_q, wqT, 768, 768);
  transpose_kernel<<<dim3(24, 24), tb, 0, stream>>>(W_k, wkT, 768, 768);
  transpose_kernel<<<dim3(24, 24), tb, 0, stream>>>(W_v, wvT, 768, 768);
  transpose_kernel<<<dim3(24, 24), tb, 0, stream>>>(W_w2e, ww2eT, 768, 768);
  transpose_kernel<<<dim3(24, 24), tb, 0, stream>>>(W_e2w, we2wT, 768, 768);
  transpose_kernel<<<dim3(24, 24), tb, 0, stream>>>(W_e2e, we2eT, 768, 768);
  transpose_kernel<<<dim3(24, 24), tb, 0, stream>>>(W_ao, waoT, 768, 768);
  transpose_kernel<<<dim3(96, 24), tb, 0, stream>>>(W_i, wiT, 768, 3072);
  transpose_kernel<<<dim3(24, 96), tb, 0, stream>>>(W_o, woT, 3072, 768);
  concat_kernel<<<3840, 256, 0, stream>>>(word, ent, xall);

  const long long TDs = (long long)T_ * D_;
  gemm_kernel<0><<<dim3(80, 6, 1), 256, 0, stream>>>(xall, wkT, bk, kb, 768, 768, 768, 0, 0);
  gemm_kernel<0><<<dim3(80, 6, 1), 256, 0, stream>>>(xall, wvT, bv, vb, 768, 768, 768, 0, 0);
  gemm_kernel<0><<<dim3(4, 6, 16), 256, 0, stream>>>(xall, wqT, bq, qw, 768, 768, 768, TDs, TDs);
  gemm_kernel<0><<<dim3(1, 6, 16), 256, 0, stream>>>(xall + (size_t)S_ * D_, we2wT, be2w,
                                                     qw + (size_t)S_ * D_, 768, 768, 768, TDs, TDs);
  gemm_kernel<0><<<dim3(4, 6, 16), 256, 0, stream>>>(xall, ww2eT, bw2e, qe, 768, 768, 768, TDs, TDs);
  gemm_kernel<0><<<dim3(1, 6, 16), 256, 0, stream>>>(xall + (size_t)S_ * D_, we2eT, be2e,
                                                     qe + (size_t)S_ * D_, 768, 768, 768, TDs, TDs);

  attn_kernel<<<dim3(40, 12, 16), 256, 0, stream>>>(qw, qe, kb, vb, mask, ctxb);

  gemm_kernel<0><<<dim3(80, 6, 1), 256, 0, stream>>>(ctxb, waoT, bao, ao_raw, 768, 768, 768, 0, 0);
  ln_kernel<0><<<10240, 256, 0, stream>>>(ao_raw, xall, gao, beao, ao);
  gemm_kernel<1><<<dim3(80, 24, 1), 256, 0, stream>>>(ao, wiT, bi, inter, 768, 3072, 768, 0, 0);
  gemm_kernel<0><<<dim3(80, 6, 1), 256, 0, stream>>>(inter, woT, bo, out_raw, 3072, 768, 3072, 0, 0);
  ln_kernel<1><<<10240, 256, 0, stream>>>(out_raw, ao, go, beo, d_out);
}

// Round 3
// 554.003 us; speedup vs baseline: 1.1952x; 1.1952x over previous
//
#include <hip/hip_runtime.h>
#include <stdint.h>

// ============================================================================
// LUKE entity-aware attention block, MI355X gfx950, round 2.
// FP32 I/O, bf16 MFMA internals. Round-2 change: attention restructured
// (q-tile 32, V pre-transposed in V-GEMM epilogue, no LDS V staging, 2
// barriers), Q-projections merged via per-m-tile weight select, transposes
// fused. 24 -> 15 dispatches.
// ============================================================================

#define B_ 16
#define S_ 512
#define E_ 128
#define T_ 640
#define D_ 768
#define H_ 12
#define DH_ 64
#define FF_ 3072
#define SCP_LD 664  // scores LDS leading dim (elems); 664*2=1328B = 16B*83

typedef unsigned short u16;
typedef __bf16 bf16x8 __attribute__((ext_vector_type(8)));
typedef u16 u16x8 __attribute__((ext_vector_type(8)));
typedef u16 u16x4 __attribute__((ext_vector_type(4)));
typedef float f32x4 __attribute__((ext_vector_type(4)));

__device__ __forceinline__ float b2f(u16 v) {
  unsigned u = ((unsigned)v) << 16;
  return __builtin_bit_cast(float, u);
}
__device__ __forceinline__ u16 f2b(float f) {  // RNE
  unsigned u = __builtin_bit_cast(unsigned, f);
  u += 0x7FFFu + ((u >> 16) & 1u);
  return (u16)(u >> 16);
}

__device__ __forceinline__ void gl_lds16(const u16* g, u16* l) {
  __builtin_amdgcn_global_load_lds((__attribute__((address_space(1))) const void*)g,
                                   (__attribute__((address_space(3))) void*)l, 16, 0, 0);
}

// ============================================================================
// GEMM: C[M,N] = A[M,K] @ Bt[N,K]^T (+bias[N]), bf16, fp32 accum.
// 128x128 tile, BK=32, 4 waves. Weight select: m-tile >= msel uses Bt1/bias1.
// EPI: 0 = bias ; 1 = bias + exact GELU ; 2 = bias + transposed V store
//   (C = Vt base, layout [b][h][dh][t], grid must be (80,6,1) flat rows)
// ============================================================================
template <int EPI>
__global__ __launch_bounds__(256) void gemm_kernel(
    const u16* __restrict__ A, const u16* __restrict__ Bt0,
    const u16* __restrict__ Bt1, const u16* __restrict__ bias0,
    const u16* __restrict__ bias1, int msel, u16* __restrict__ C,
    int lda, int ldc, int K, long long sA, long long sC) {
  __shared__ __align__(16) u16 As[128 * 32];
  __shared__ __align__(16) u16 Bs[128 * 32];

  const int tid = threadIdx.x;
  const int m0 = blockIdx.x * 128, n0 = blockIdx.y * 128;
  const u16* Bt = (blockIdx.x >= msel) ? Bt1 : Bt0;
  const u16* bias = (blockIdx.x >= msel) ? bias1 : bias0;
  A += (long long)blockIdx.z * sA + (long long)m0 * lda;
  Bt += (long long)n0 * K;
  C += (long long)blockIdx.z * sC;

  const int lane = tid & 63, wave = tid >> 6;
  const int wm = (wave & 1) << 6, wn = (wave >> 1) << 6;
  const int l15 = lane & 15, quad = lane >> 4;

  const int r0 = tid >> 2, c0 = (tid & 3) << 3;
  const u16* ga0 = A + (long long)r0 * lda + c0;
  const u16* ga1 = A + (long long)(r0 + 64) * lda + c0;
  const u16* gb0 = Bt + (long long)r0 * K + c0;
  const u16* gb1 = Bt + (long long)(r0 + 64) * K + c0;

  f32x4 acc[4][4] = {};

  for (int k0 = 0; k0 < K; k0 += 32) {
    __syncthreads();
    gl_lds16(ga0 + k0, &As[tid * 8]);
    gl_lds16(ga1 + k0, &As[2048 + tid * 8]);
    gl_lds16(gb0 + k0, &Bs[tid * 8]);
    gl_lds16(gb1 + k0, &Bs[2048 + tid * 8]);
    __syncthreads();

    bf16x8 af[4], bfr[4];
#pragma unroll
    for (int i = 0; i < 4; i++)
      af[i] = *(const bf16x8*)&As[(wm + i * 16 + l15) * 32 + quad * 8];
#pragma unroll
    for (int i = 0; i < 4; i++)
      bfr[i] = *(const bf16x8*)&Bs[(wn + i * 16 + l15) * 32 + quad * 8];
#pragma unroll
    for (int i = 0; i < 4; i++)
#pragma unroll
      for (int j = 0; j < 4; j++)
        acc[i][j] = __builtin_amdgcn_mfma_f32_16x16x32_bf16(af[i], bfr[j], acc[i][j], 0, 0, 0);
  }

  float bv[4];
#pragma unroll
  for (int j = 0; j < 4; j++) bv[j] = b2f(bias[n0 + wn + j * 16 + l15]);

  if (EPI == 2) {
    // transposed V store: Vt[((b*H + h)*DH + dh)*T + t], 4 consecutive t per store
#pragma unroll
    for (int i = 0; i < 4; i++) {
      const int grow = m0 + wm + i * 16 + quad * 4;  // flat token row
      const int bb = grow / T_, tt = grow - bb * T_;
#pragma unroll
      for (int j = 0; j < 4; j++) {
        const int col = n0 + wn + j * 16 + l15;  // h*64 + dh
        u16x4 pk;
#pragma unroll
        for (int r = 0; r < 4; r++) pk[r] = f2b(acc[i][j][r] + bv[j]);
        *(u16x4*)&C[(((long long)bb * H_ + (col >> 6)) * DH_ + (col & 63)) * T_ + tt] = pk;
      }
    }
  } else {
#pragma unroll
    for (int i = 0; i < 4; i++) {
      const int row = m0 + wm + i * 16 + quad * 4;
#pragma unroll
      for (int j = 0; j < 4; j++) {
        const int col = n0 + wn + j * 16 + l15;
#pragma unroll
        for (int r = 0; r < 4; r++) {
          float v = acc[i][j][r] + bv[j];
          if (EPI == 1) v = 0.5f * v * (1.0f + erff(v * 0.70710678118654752f));
          C[(long long)(row + r) * ldc + col] = f2b(v);
        }
      }
    }
  }
}

// ============================================================================
// Fused attention v2: block = (b, h, 32-query tile). Wave w covers keys
// [w*160, w*160+160). Scores in LDS (stride SCP_LD), deferred softmax norm.
// Phase 3 reads V fragments directly from pre-transposed Vt (no LDS staging,
// no barriers). 2 __syncthreads total.
// ============================================================================
__global__ __launch_bounds__(256) void attn_kernel(
    const u16* __restrict__ Qw, const u16* __restrict__ Qe,
    const u16* __restrict__ Kb, const u16* __restrict__ Vt,
    const float* __restrict__ mask, u16* __restrict__ ctx) {
  const int q0 = blockIdx.x * 32;
  const int h = blockIdx.y, b = blockIdx.z;

  __shared__ __align__(16) u16 scp[32 * SCP_LD];
  __shared__ float rsum[32];

  const int tid = threadIdx.x;
  const int lane = tid & 63, wave = tid >> 6;
  const int l15 = lane & 15, quad = lane >> 4;

  const long long bh = (long long)b * T_ * D_ + h * DH_;
  const long long bhV = ((long long)b * H_ + h) * DH_ * T_;

  // Q fragments: [q-group][w/e][k-half]
  bf16x8 qf[2][2][2];
#pragma unroll
  for (int g = 0; g < 2; g++) {
    const u16* qwp = Qw + bh + (long long)(q0 + g * 16 + l15) * D_ + quad * 8;
    const u16* qep = Qe + bh + (long long)(q0 + g * 16 + l15) * D_ + quad * 8;
    qf[g][0][0] = *(const bf16x8*)(qwp);
    qf[g][0][1] = *(const bf16x8*)(qwp + 32);
    qf[g][1][0] = *(const bf16x8*)(qep);
    qf[g][1][1] = *(const bf16x8*)(qep + 32);
  }

  // ---- phase 1: scores ---------------------------------------------------
#pragma unroll
  for (int i = 0; i < 10; i++) {
    const int key0 = wave * 160 + i * 16;  // wave-uniform, 16-aligned
    const u16* kp = Kb + bh + (long long)(key0 + l15) * D_ + quad * 8;
    const bf16x8 kf0 = *(const bf16x8*)(kp);
    const bf16x8 kf1 = *(const bf16x8*)(kp + 32);
    const float mv = mask[b * T_ + key0 + l15];
    const int e = (key0 < S_) ? 0 : 1;  // wave-uniform
#pragma unroll
    for (int g = 0; g < 2; g++) {
      f32x4 a = {0.f, 0.f, 0.f, 0.f};
      a = __builtin_amdgcn_mfma_f32_16x16x32_bf16(qf[g][e][0], kf0, a, 0, 0, 0);
      a = __builtin_amdgcn_mfma_f32_16x16x32_bf16(qf[g][e][1], kf1, a, 0, 0, 0);
#pragma unroll
      for (int r = 0; r < 4; r++)
        scp[(g * 16 + quad * 4 + r) * SCP_LD + key0 + l15] = f2b(a[r] * 0.125f + mv);
    }
  }
  __syncthreads();

  // ---- phase 2: softmax (vectorized, unnormalized; row sums kept) -------
  {
    const int row = tid >> 3, ck = tid & 7;  // 8 threads per row
    float mx = -1e30f;
#pragma unroll
    for (int c = 0; c < 10; c++) {
      const u16x8 v = *(const u16x8*)&scp[row * SCP_LD + c * 64 + ck * 8];
#pragma unroll
      for (int e = 0; e < 8; e++) mx = fmaxf(mx, b2f(v[e]));
    }
#pragma unroll
    for (int d = 4; d; d >>= 1) mx = fmaxf(mx, __shfl_xor(mx, d, 8));
    float sum = 0.f;
#pragma unroll
    for (int c = 0; c < 10; c++) {
      u16* p = &scp[row * SCP_LD + c * 64 + ck * 8];
      const u16x8 v = *(const u16x8*)p;
      u16x8 o;
#pragma unroll
      for (int e = 0; e < 8; e++) {
        const float ex = __expf(b2f(v[e]) - mx);
        sum += ex;
        o[e] = f2b(ex);
      }
      *(u16x8*)p = o;
    }
#pragma unroll
    for (int d = 4; d; d >>= 1) sum += __shfl_xor(sum, d, 8);
    if (ck == 0) rsum[row] = sum;
  }
  __syncthreads();

  // ---- phase 3: ctx = P V via Vt (wave w owns dh [w*16, w*16+16)) --------
  f32x4 o0 = {0.f, 0.f, 0.f, 0.f}, o1 = {0.f, 0.f, 0.f, 0.f};
  const u16* vrow = Vt + bhV + (long long)(wave * 16 + l15) * T_;
#pragma unroll
  for (int kc = 0; kc < T_; kc += 64) {
#pragma unroll
    for (int ks = 0; ks < 2; ks++) {
      const int ko = kc + ks * 32 + quad * 8;
      const bf16x8 vf = *(const bf16x8*)(vrow + ko);
      const bf16x8 p0 = *(const bf16x8*)&scp[l15 * SCP_LD + ko];
      const bf16x8 p1 = *(const bf16x8*)&scp[(16 + l15) * SCP_LD + ko];
      o0 = __builtin_amdgcn_mfma_f32_16x16x32_bf16(p0, vf, o0, 0, 0, 0);
      o1 = __builtin_amdgcn_mfma_f32_16x16x32_bf16(p1, vf, o1, 0, 0, 0);
    }
  }

  u16* cp0 = ctx + bh + (long long)(q0 + quad * 4) * D_ + wave * 16 + l15;
#pragma unroll
  for (int r = 0; r < 4; r++) cp0[(long long)r * D_] = f2b(o0[r] / rsum[quad * 4 + r]);
  u16* cp1 = ctx + bh + (long long)(q0 + 16 + quad * 4) * D_ + wave * 16 + l15;
#pragma unroll
  for (int r = 0; r < 4; r++) cp1[(long long)r * D_] = f2b(o1[r] / rsum[16 + quad * 4 + r]);
}

// ============================================================================
// LayerNorm over D=768 with fused residual add. SPLIT=1: scatter rows into
// [word | entity] fp32 output (d_out). SPLIT=0: bf16 out.
// ============================================================================
template <int SPLIT>
__global__ __launch_bounds__(256) void ln_kernel(
    const u16* __restrict__ x, const u16* __restrict__ res,
    const u16* __restrict__ g, const u16* __restrict__ beta,
    void* __restrict__ out_) {
  const int row = blockIdx.x;
  const int tid = threadIdx.x;
  const u16* xp = x + (long long)row * D_;
  const u16* rp = res + (long long)row * D_;
  float v[3], s = 0.f, s2 = 0.f;
#pragma unroll
  for (int i = 0; i < 3; i++) {
    const int c = tid + i * 256;
    v[i] = b2f(xp[c]) + b2f(rp[c]);
    s += v[i];
    s2 += v[i] * v[i];
  }
#pragma unroll
  for (int d = 32; d; d >>= 1) {
    s += __shfl_xor(s, d, 64);
    s2 += __shfl_xor(s2, d, 64);
  }
  __shared__ float red[8];
  const int wave = tid >> 6;
  if ((tid & 63) == 0) { red[wave * 2] = s; red[wave * 2 + 1] = s2; }
  __syncthreads();
  s = red[0] + red[2] + red[4] + red[6];
  s2 = red[1] + red[3] + red[5] + red[7];
  const float mean = s * (1.f / 768.f);
  const float var = s2 * (1.f / 768.f) - mean * mean;
  const float rs = rsqrtf(var + 1e-12f);
  if (SPLIT) {
    float* out = (float*)out_;
    const int b = row / T_, t = row % T_;
    float* op = (t < S_) ? out + ((long long)b * S_ + t) * D_
                         : out + (long long)B_ * S_ * D_ + ((long long)b * E_ + (t - S_)) * D_;
#pragma unroll
    for (int i = 0; i < 3; i++) {
      const int c = tid + i * 256;
      op[c] = (v[i] - mean) * rs * b2f(g[c]) + b2f(beta[c]);
    }
  } else {
    u16* op = (u16*)out_ + (long long)row * D_;
#pragma unroll
    for (int i = 0; i < 3; i++) {
      const int c = tid + i * 256;
      op[c] = f2b((v[i] - mean) * rs * b2f(g[c]) + b2f(beta[c]));
    }
  }
}

// out[N,K] = bf16( in[K,N]^T ), in fp32. tiled 32x32, block (32,8)
__global__ __launch_bounds__(256) void transpose_kernel(
    const float* __restrict__ in, u16* __restrict__ out, int K, int N) {
  __shared__ u16 t[32][33];
  const int n0 = blockIdx.x * 32, k0 = blockIdx.y * 32;
  const int tx = threadIdx.x, ty = threadIdx.y;
#pragma unroll
  for (int i = 0; i < 4; i++)
    t[ty + i * 8][tx] = f2b(in[(long long)(k0 + ty + i * 8) * N + n0 + tx]);
  __syncthreads();
#pragma unroll
  for (int i = 0; i < 4; i++)
    out[(long long)(n0 + ty + i * 8) * K + k0 + tx] = t[tx][ty + i * 8];
}

// seven fused 768x768 transposes (grid z = which)
struct T7 { const float* s[7]; u16* d[7]; };
__global__ __launch_bounds__(256) void transpose7_kernel(T7 a) {
  __shared__ u16 t[32][33];
  const float* in = a.s[blockIdx.z];
  u16* out = a.d[blockIdx.z];
  const int n0 = blockIdx.x * 32, k0 = blockIdx.y * 32;
  const int tx = threadIdx.x, ty = threadIdx.y;
#pragma unroll
  for (int i = 0; i < 4; i++)
    t[ty + i * 8][tx] = f2b(in[(long long)(k0 + ty + i * 8) * 768 + n0 + tx]);
  __syncthreads();
#pragma unroll
  for (int i = 0; i < 4; i++)
    out[(long long)(n0 + ty + i * 8) * 768 + k0 + tx] = t[tx][ty + i * 8];
}

// xall[b,0:S]=word[b], xall[b,S:T]=entity[b]; fp32 in -> bf16 out
__global__ __launch_bounds__(256) void concat_kernel(
    const float* __restrict__ w, const float* __restrict__ e, u16* __restrict__ x) {
  const long long i = (long long)(blockIdx.x * 256 + threadIdx.x) * 8;
  const long long NW = (long long)B_ * S_ * D_;
  const long long NE = (long long)B_ * E_ * D_;
  const long long SD = (long long)S_ * D_;
  const long long ED = (long long)E_ * D_;
  const long long TD = (long long)T_ * D_;
  const float* src;
  u16* dst;
  if (i < NW) {
    const long long b = i / SD, r = i % SD;
    src = w + i;
    dst = &x[b * TD + r];
  } else {
    const long long j = i - NW;
    if (j >= NE) return;
    const long long b = j / ED, r = j % ED;
    src = e + j;
    dst = &x[b * TD + SD + r];
  }
  const float4 f0 = *(const float4*)(src);
  const float4 f1 = *(const float4*)(src + 4);
  u16x8 o;
  o[0] = f2b(f0.x); o[1] = f2b(f0.y); o[2] = f2b(f0.z); o[3] = f2b(f0.w);
  o[4] = f2b(f1.x); o[5] = f2b(f1.y); o[6] = f2b(f1.z); o[7] = f2b(f1.w);
  *(u16x8*)dst = o;
}

// 13 small fp32 vectors -> bf16
struct CvtArgs { const float* src[13]; u16* dst[13]; int n[13]; };
__global__ __launch_bounds__(256) void cvt_vecs_kernel(CvtArgs a) {
  const int v = blockIdx.x;
  const float* s = a.src[v];
  u16* d = a.dst[v];
  const int n = a.n[v];
  for (int i = threadIdx.x; i < n; i += 256) d[i] = f2b(s[i]);
}

extern "C" void kernel_launch(void* const* d_in, const int* in_sizes, int n_in,
                              void* d_out, int out_size, void* d_ws, size_t ws_size,
                              hipStream_t stream) {
  (void)in_sizes; (void)n_in; (void)out_size; (void)ws_size;
  const float* word = (const float*)d_in[0];
  const float* ent = (const float*)d_in[1];
  const float* mask = (const float*)d_in[2];
  const float* W_q = (const float*)d_in[3];
  const float* b_q = (const float*)d_in[4];
  const float* W_k = (const float*)d_in[5];
  const float* b_k = (const float*)d_in[6];
  const float* W_v = (const float*)d_in[7];
  const float* b_v = (const float*)d_in[8];
  const float* W_w2e = (const float*)d_in[9];
  const float* b_w2e = (const float*)d_in[10];
  const float* W_e2w = (const float*)d_in[11];
  const float* b_e2w = (const float*)d_in[12];
  const float* W_e2e = (const float*)d_in[13];
  const float* b_e2e = (const float*)d_in[14];
  const float* W_ao = (const float*)d_in[15];
  const float* b_ao = (const float*)d_in[16];
  const float* g_ao = (const float*)d_in[17];
  const float* be_ao = (const float*)d_in[18];
  const float* W_i = (const float*)d_in[19];
  const float* b_i = (const float*)d_in[20];
  const float* W_o = (const float*)d_in[21];
  const float* b_o = (const float*)d_in[22];
  const float* g_o = (const float*)d_in[23];
  const float* be_o = (const float*)d_in[24];

  const size_t DD = (size_t)D_ * D_ * 2;
  const size_t DFF = (size_t)D_ * FF_ * 2;
  const size_t TD = (size_t)B_ * T_ * D_ * 2;
  size_t off = 0;
  char* base = (char*)d_ws;
  auto take = [&](size_t n) { void* p = base + off; off += n; return p; };
  u16* wqT = (u16*)take(DD);
  u16* wkT = (u16*)take(DD);
  u16* wvT = (u16*)take(DD);
  u16* ww2eT = (u16*)take(DD);
  u16* we2wT = (u16*)take(DD);
  u16* we2eT = (u16*)take(DD);
  u16* waoT = (u16*)take(DD);
  u16* wiT = (u16*)take(DFF);
  u16* woT = (u16*)take(DFF);
  u16* vecs = (u16*)take(2 * 16384);
  u16* xall = (u16*)take(TD);
  u16* qw = (u16*)take(TD);
  u16* qe = (u16*)take(TD);
  u16* kb = (u16*)take(TD);
  u16* vt = (u16*)take(TD);  // Vt [b][h][dh][t] = 12.6 MB <= TD slot
  u16* ctxb = (u16*)take(TD);
  u16* inter = (u16*)take((size_t)B_ * T_ * FF_ * 2);
  u16* bq = vecs + 0 * 768;
  u16* bk = vecs + 1 * 768;
  u16* bv = vecs + 2 * 768;
  u16* bw2e = vecs + 3 * 768;
  u16* be2w = vecs + 4 * 768;
  u16* be2e = vecs + 5 * 768;
  u16* bao = vecs + 6 * 768;
  u16* gao = vecs + 7 * 768;
  u16* beao = vecs + 8 * 768;
  u16* bo = vecs + 9 * 768;
  u16* go = vecs + 10 * 768;
  u16* beo = vecs + 11 * 768;
  u16* bi = vecs + 12 * 768;  // 3072 elems
  u16* ao_raw = qw;
  u16* ao = kb;
  u16* out_raw = qe;

  CvtArgs ca;
  ca.src[0] = b_q;   ca.dst[0] = bq;   ca.n[0] = 768;
  ca.src[1] = b_k;   ca.dst[1] = bk;   ca.n[1] = 768;
  ca.src[2] = b_v;   ca.dst[2] = bv;   ca.n[2] = 768;
  ca.src[3] = b_w2e; ca.dst[3] = bw2e; ca.n[3] = 768;
  ca.src[4] = b_e2w; ca.dst[4] = be2w; ca.n[4] = 768;
  ca.src[5] = b_e2e; ca.dst[5] = be2e; ca.n[5] = 768;
  ca.src[6] = b_ao;  ca.dst[6] = bao;  ca.n[6] = 768;
  ca.src[7] = g_ao;  ca.dst[7] = gao;  ca.n[7] = 768;
  ca.src[8] = be_ao; ca.dst[8] = beao; ca.n[8] = 768;
  ca.src[9] = b_o;   ca.dst[9] = bo;   ca.n[9] = 768;
  ca.src[10] = g_o;  ca.dst[10] = go;  ca.n[10] = 768;
  ca.src[11] = be_o; ca.dst[11] = beo; ca.n[11] = 768;
  ca.src[12] = b_i;  ca.dst[12] = bi;  ca.n[12] = 3072;
  cvt_vecs_kernel<<<13, 256, 0, stream>>>(ca);

  T7 t7;
  t7.s[0] = W_q;   t7.d[0] = wqT;
  t7.s[1] = W_k;   t7.d[1] = wkT;
  t7.s[2] = W_v;   t7.d[2] = wvT;
  t7.s[3] = W_w2e; t7.d[3] = ww2eT;
  t7.s[4] = W_e2w; t7.d[4] = we2wT;
  t7.s[5] = W_e2e; t7.d[5] = we2eT;
  t7.s[6] = W_ao;  t7.d[6] = waoT;
  const dim3 tb(32, 8);
  transpose7_kernel<<<dim3(24, 24, 7), tb, 0, stream>>>(t7);
  transpose_kernel<<<dim3(96, 24), tb, 0, stream>>>(W_i, wiT, 768, 3072);
  transpose_kernel<<<dim3(24, 96), tb, 0, stream>>>(W_o, woT, 3072, 768);
  concat_kernel<<<3840, 256, 0, stream>>>(word, ent, xall);

  const long long TDs = (long long)T_ * D_;
  const int BIG = 1 << 30;
  // K projection (flat rows), V projection with transposed store
  gemm_kernel<0><<<dim3(80, 6, 1), 256, 0, stream>>>(xall, wkT, wkT, bk, bk, BIG, kb, 768, 768, 768, 0, 0);
  gemm_kernel<2><<<dim3(80, 6, 1), 256, 0, stream>>>(xall, wvT, wvT, bv, bv, BIG, vt, 768, 0, 768, 0, 0);
  // Qw = [word@W_q ; ent@W_e2w], Qe = [word@W_w2e ; ent@W_e2e]: m-tile 4 = entity
  gemm_kernel<0><<<dim3(5, 6, 16), 256, 0, stream>>>(xall, wqT, we2wT, bq, be2w, 4, qw, 768, 768, 768, TDs, TDs);
  gemm_kernel<0><<<dim3(5, 6, 16), 256, 0, stream>>>(xall, ww2eT, we2eT, bw2e, be2e, 4, qe, 768, 768, 768, TDs, TDs);

  attn_kernel<<<dim3(20, 12, 16), 256, 0, stream>>>(qw, qe, kb, vt, mask, ctxb);

  gemm_kernel<0><<<dim3(80, 6, 1), 256, 0, stream>>>(ctxb, waoT, waoT, bao, bao, BIG, ao_raw, 768, 768, 768, 0, 0);
  ln_kernel<0><<<10240, 256, 0, stream>>>(ao_raw, xall, gao, beao, ao);
  gemm_kernel<1><<<dim3(80, 24, 1), 256, 0, stream>>>(ao, wiT, wiT, bi, bi, BIG, inter, 768, 3072, 768, 0, 0);
  gemm_kernel<0><<<dim3(80, 6, 1), 256, 0, stream>>>(inter, woT, woT, bo, bo, BIG, out_raw, 3072, 768, 3072, 0, 0);
  ln_kernel<1><<<10240, 256, 0, stream>>>(out_raw, ao, go, beo, d_out);
}

// Round 4
// 510.170 us; speedup vs baseline: 1.2979x; 1.0859x over previous
//
#include <hip/hip_runtime.h>
#include <stdint.h>

// ============================================================================
// LUKE entity-aware attention block, MI355X gfx950, round 3.
// FP32 I/O, bf16 MFMA internals. Round-3 change: GEMM BK=64 (two BK=32
// panels, 32 MFMA per barrier-pair) to amortize the per-iter vmcnt(0)+barrier
// drain; K+V projections merged into one launch; Qw+Qe merged into one
// launch. 15 -> 13 dispatches.
// ============================================================================

#define B_ 16
#define S_ 512
#define E_ 128
#define T_ 640
#define D_ 768
#define H_ 12
#define DH_ 64
#define FF_ 3072
#define SCP_LD 664

typedef unsigned short u16;
typedef __bf16 bf16x8 __attribute__((ext_vector_type(8)));
typedef u16 u16x8 __attribute__((ext_vector_type(8)));
typedef u16 u16x4 __attribute__((ext_vector_type(4)));
typedef float f32x4 __attribute__((ext_vector_type(4)));

__device__ __forceinline__ float b2f(u16 v) {
  unsigned u = ((unsigned)v) << 16;
  return __builtin_bit_cast(float, u);
}
__device__ __forceinline__ u16 f2b(float f) {  // RNE
  unsigned u = __builtin_bit_cast(unsigned, f);
  u += 0x7FFFu + ((u >> 16) & 1u);
  return (u16)(u >> 16);
}

__device__ __forceinline__ void gl_lds16(const u16* g, u16* l) {
  __builtin_amdgcn_global_load_lds((__attribute__((address_space(1))) const void*)g,
                                   (__attribute__((address_space(3))) void*)l, 16, 0, 0);
}

// ============================================================================
// GEMM core: 128x128 tile, BK=64 as two BK=32 panels (verified m97 LDS
// pattern per panel), 4 waves (2x2 of 64x64), 32 MFMA per barrier-pair.
// As/Bs: 8192 u16 each (panel p at offset p*4096).
// ============================================================================
__device__ __forceinline__ void gemm_core(
    const u16* __restrict__ A, const u16* __restrict__ Bt, int lda, int K,
    u16* As, u16* Bs, f32x4 (&acc)[4][4]) {
  const int tid = threadIdx.x;
  const int lane = tid & 63, wave = tid >> 6;
  const int wm = (wave & 1) << 6, wn = (wave >> 1) << 6;
  const int l15 = lane & 15, quad = lane >> 4;

  const int r0 = tid >> 2, c0 = (tid & 3) << 3;
  const u16* ga0 = A + (long long)r0 * lda + c0;
  const u16* ga1 = A + (long long)(r0 + 64) * lda + c0;
  const u16* gb0 = Bt + (long long)r0 * K + c0;
  const u16* gb1 = Bt + (long long)(r0 + 64) * K + c0;

  for (int k0 = 0; k0 < K; k0 += 64) {
    __syncthreads();
    gl_lds16(ga0 + k0, &As[tid * 8]);
    gl_lds16(ga1 + k0, &As[2048 + tid * 8]);
    gl_lds16(ga0 + k0 + 32, &As[4096 + tid * 8]);
    gl_lds16(ga1 + k0 + 32, &As[6144 + tid * 8]);
    gl_lds16(gb0 + k0, &Bs[tid * 8]);
    gl_lds16(gb1 + k0, &Bs[2048 + tid * 8]);
    gl_lds16(gb0 + k0 + 32, &Bs[4096 + tid * 8]);
    gl_lds16(gb1 + k0 + 32, &Bs[6144 + tid * 8]);
    __syncthreads();

#pragma unroll
    for (int p = 0; p < 2; p++) {
      bf16x8 af[4], bfr[4];
#pragma unroll
      for (int i = 0; i < 4; i++)
        af[i] = *(const bf16x8*)&As[p * 4096 + (wm + i * 16 + l15) * 32 + quad * 8];
#pragma unroll
      for (int i = 0; i < 4; i++)
        bfr[i] = *(const bf16x8*)&Bs[p * 4096 + (wn + i * 16 + l15) * 32 + quad * 8];
#pragma unroll
      for (int i = 0; i < 4; i++)
#pragma unroll
        for (int j = 0; j < 4; j++)
          acc[i][j] = __builtin_amdgcn_mfma_f32_16x16x32_bf16(af[i], bfr[j], acc[i][j], 0, 0, 0);
    }
  }
}

__device__ __forceinline__ void epi_store(
    f32x4 (&acc)[4][4], const u16* __restrict__ bias, u16* __restrict__ C,
    int m0, int n0, int ldc, bool gelu) {
  const int tid = threadIdx.x;
  const int lane = tid & 63, wave = tid >> 6;
  const int wm = (wave & 1) << 6, wn = (wave >> 1) << 6;
  const int l15 = lane & 15, quad = lane >> 4;
  float bv[4];
#pragma unroll
  for (int j = 0; j < 4; j++) bv[j] = b2f(bias[n0 + wn + j * 16 + l15]);
#pragma unroll
  for (int i = 0; i < 4; i++) {
    const int row = m0 + wm + i * 16 + quad * 4;
#pragma unroll
    for (int j = 0; j < 4; j++) {
      const int col = n0 + wn + j * 16 + l15;
#pragma unroll
      for (int r = 0; r < 4; r++) {
        float v = acc[i][j][r] + bv[j];
        if (gelu) v = 0.5f * v * (1.0f + erff(v * 0.70710678118654752f));
        C[(long long)(row + r) * ldc + col] = f2b(v);
      }
    }
  }
}

// MODE 0: plain C = A@Bt^T + bias (EPI gelu flag), strided batch via z
// MODE 1: merged KV: y<6 -> K-proj normal store; y>=6 -> V transposed store
// MODE 2: merged Q: y<6 -> Qw (Bt by m-tile), y>=6 -> Qe
template <int MODE, bool GELU>
__global__ __launch_bounds__(256) void gemm_kernel(
    const u16* __restrict__ A, const u16* __restrict__ Bt0,
    const u16* __restrict__ Bt1, const u16* __restrict__ Bt2,
    const u16* __restrict__ Bt3, const u16* __restrict__ bias0,
    const u16* __restrict__ bias1, const u16* __restrict__ bias2,
    const u16* __restrict__ bias3, u16* __restrict__ C0, u16* __restrict__ C1,
    int lda, int ldc, int K, long long sA, long long sC) {
  __shared__ __align__(16) u16 As[8192];
  __shared__ __align__(16) u16 Bs[8192];

  const int m0 = blockIdx.x * 128;
  int n0;
  const u16 *Bt, *bias;
  u16* C;
  bool vstore = false;
  if (MODE == 0) {
    n0 = blockIdx.y * 128;
    Bt = Bt0; bias = bias0; C = C0;
  } else if (MODE == 1) {
    if (blockIdx.y < 6) { n0 = blockIdx.y * 128; Bt = Bt0; bias = bias0; C = C0; }
    else { n0 = (blockIdx.y - 6) * 128; Bt = Bt1; bias = bias1; C = C1; vstore = true; }
  } else {  // MODE 2
    const bool isE = (blockIdx.x >= 4);
    if (blockIdx.y < 6) {
      n0 = blockIdx.y * 128;
      Bt = isE ? Bt1 : Bt0; bias = isE ? bias1 : bias0; C = C0;
    } else {
      n0 = (blockIdx.y - 6) * 128;
      Bt = isE ? Bt3 : Bt2; bias = isE ? bias3 : bias2; C = C1;
    }
  }

  const u16* Ab = A + (long long)blockIdx.z * sA + (long long)m0 * lda;
  C += (long long)blockIdx.z * sC;

  f32x4 acc[4][4] = {};
  gemm_core(Ab, Bt + (long long)n0 * K, lda, K, As, Bs, acc);

  if (MODE == 1 && vstore) {
    // transposed V store: Vt[((b*H + h)*DH + dh)*T + t]
    const int tid = threadIdx.x;
    const int lane = tid & 63, wave = tid >> 6;
    const int wm = (wave & 1) << 6, wn = (wave >> 1) << 6;
    const int l15 = lane & 15, quad = lane >> 4;
    float bv[4];
#pragma unroll
    for (int j = 0; j < 4; j++) bv[j] = b2f(bias[n0 + wn + j * 16 + l15]);
#pragma unroll
    for (int i = 0; i < 4; i++) {
      const int grow = m0 + wm + i * 16 + quad * 4;
      const int bb = grow / T_, tt = grow - bb * T_;
#pragma unroll
      for (int j = 0; j < 4; j++) {
        const int col = n0 + wn + j * 16 + l15;
        u16x4 pk;
#pragma unroll
        for (int r = 0; r < 4; r++) pk[r] = f2b(acc[i][j][r] + bv[j]);
        *(u16x4*)&C[(((long long)bb * H_ + (col >> 6)) * DH_ + (col & 63)) * T_ + tt] = pk;
      }
    }
  } else {
    epi_store(acc, bias, C, m0, n0, ldc, GELU);
  }
}

// ============================================================================
// Fused attention (round-2 structure, unchanged): block = (b, h, 32-q tile).
// ============================================================================
__global__ __launch_bounds__(256) void attn_kernel(
    const u16* __restrict__ Qw, const u16* __restrict__ Qe,
    const u16* __restrict__ Kb, const u16* __restrict__ Vt,
    const float* __restrict__ mask, u16* __restrict__ ctx) {
  const int q0 = blockIdx.x * 32;
  const int h = blockIdx.y, b = blockIdx.z;

  __shared__ __align__(16) u16 scp[32 * SCP_LD];
  __shared__ float rsum[32];

  const int tid = threadIdx.x;
  const int lane = tid & 63, wave = tid >> 6;
  const int l15 = lane & 15, quad = lane >> 4;

  const long long bh = (long long)b * T_ * D_ + h * DH_;
  const long long bhV = ((long long)b * H_ + h) * DH_ * T_;

  bf16x8 qf[2][2][2];
#pragma unroll
  for (int g = 0; g < 2; g++) {
    const u16* qwp = Qw + bh + (long long)(q0 + g * 16 + l15) * D_ + quad * 8;
    const u16* qep = Qe + bh + (long long)(q0 + g * 16 + l15) * D_ + quad * 8;
    qf[g][0][0] = *(const bf16x8*)(qwp);
    qf[g][0][1] = *(const bf16x8*)(qwp + 32);
    qf[g][1][0] = *(const bf16x8*)(qep);
    qf[g][1][1] = *(const bf16x8*)(qep + 32);
  }

#pragma unroll
  for (int i = 0; i < 10; i++) {
    const int key0 = wave * 160 + i * 16;
    const u16* kp = Kb + bh + (long long)(key0 + l15) * D_ + quad * 8;
    const bf16x8 kf0 = *(const bf16x8*)(kp);
    const bf16x8 kf1 = *(const bf16x8*)(kp + 32);
    const float mv = mask[b * T_ + key0 + l15];
    const int e = (key0 < S_) ? 0 : 1;
#pragma unroll
    for (int g = 0; g < 2; g++) {
      f32x4 a = {0.f, 0.f, 0.f, 0.f};
      a = __builtin_amdgcn_mfma_f32_16x16x32_bf16(qf[g][e][0], kf0, a, 0, 0, 0);
      a = __builtin_amdgcn_mfma_f32_16x16x32_bf16(qf[g][e][1], kf1, a, 0, 0, 0);
#pragma unroll
      for (int r = 0; r < 4; r++)
        scp[(g * 16 + quad * 4 + r) * SCP_LD + key0 + l15] = f2b(a[r] * 0.125f + mv);
    }
  }
  __syncthreads();

  {
    const int row = tid >> 3, ck = tid & 7;
    float mx = -1e30f;
#pragma unroll
    for (int c = 0; c < 10; c++) {
      const u16x8 v = *(const u16x8*)&scp[row * SCP_LD + c * 64 + ck * 8];
#pragma unroll
      for (int e = 0; e < 8; e++) mx = fmaxf(mx, b2f(v[e]));
    }
#pragma unroll
    for (int d = 4; d; d >>= 1) mx = fmaxf(mx, __shfl_xor(mx, d, 8));
    float sum = 0.f;
#pragma unroll
    for (int c = 0; c < 10; c++) {
      u16* p = &scp[row * SCP_LD + c * 64 + ck * 8];
      const u16x8 v = *(const u16x8*)p;
      u16x8 o;
#pragma unroll
      for (int e = 0; e < 8; e++) {
        const float ex = __expf(b2f(v[e]) - mx);
        sum += ex;
        o[e] = f2b(ex);
      }
      *(u16x8*)p = o;
    }
#pragma unroll
    for (int d = 4; d; d >>= 1) sum += __shfl_xor(sum, d, 8);
    if (ck == 0) rsum[row] = sum;
  }
  __syncthreads();

  f32x4 o0 = {0.f, 0.f, 0.f, 0.f}, o1 = {0.f, 0.f, 0.f, 0.f};
  const u16* vrow = Vt + bhV + (long long)(wave * 16 + l15) * T_;
#pragma unroll
  for (int kc = 0; kc < T_; kc += 64) {
#pragma unroll
    for (int ks = 0; ks < 2; ks++) {
      const int ko = kc + ks * 32 + quad * 8;
      const bf16x8 vf = *(const bf16x8*)(vrow + ko);
      const bf16x8 p0 = *(const bf16x8*)&scp[l15 * SCP_LD + ko];
      const bf16x8 p1 = *(const bf16x8*)&scp[(16 + l15) * SCP_LD + ko];
      o0 = __builtin_amdgcn_mfma_f32_16x16x32_bf16(p0, vf, o0, 0, 0, 0);
      o1 = __builtin_amdgcn_mfma_f32_16x16x32_bf16(p1, vf, o1, 0, 0, 0);
    }
  }

  u16* cp0 = ctx + bh + (long long)(q0 + quad * 4) * D_ + wave * 16 + l15;
#pragma unroll
  for (int r = 0; r < 4; r++) cp0[(long long)r * D_] = f2b(o0[r] / rsum[quad * 4 + r]);
  u16* cp1 = ctx + bh + (long long)(q0 + 16 + quad * 4) * D_ + wave * 16 + l15;
#pragma unroll
  for (int r = 0; r < 4; r++) cp1[(long long)r * D_] = f2b(o1[r] / rsum[16 + quad * 4 + r]);
}

// ============================================================================
// LayerNorm over D=768 with fused residual add.
// ============================================================================
template <int SPLIT>
__global__ __launch_bounds__(256) void ln_kernel(
    const u16* __restrict__ x, const u16* __restrict__ res,
    const u16* __restrict__ g, const u16* __restrict__ beta,
    void* __restrict__ out_) {
  const int row = blockIdx.x;
  const int tid = threadIdx.x;
  const u16* xp = x + (long long)row * D_;
  const u16* rp = res + (long long)row * D_;
  float v[3], s = 0.f, s2 = 0.f;
#pragma unroll
  for (int i = 0; i < 3; i++) {
    const int c = tid + i * 256;
    v[i] = b2f(xp[c]) + b2f(rp[c]);
    s += v[i];
    s2 += v[i] * v[i];
  }
#pragma unroll
  for (int d = 32; d; d >>= 1) {
    s += __shfl_xor(s, d, 64);
    s2 += __shfl_xor(s2, d, 64);
  }
  __shared__ float red[8];
  const int wave = tid >> 6;
  if ((tid & 63) == 0) { red[wave * 2] = s; red[wave * 2 + 1] = s2; }
  __syncthreads();
  s = red[0] + red[2] + red[4] + red[6];
  s2 = red[1] + red[3] + red[5] + red[7];
  const float mean = s * (1.f / 768.f);
  const float var = s2 * (1.f / 768.f) - mean * mean;
  const float rs = rsqrtf(var + 1e-12f);
  if (SPLIT) {
    float* out = (float*)out_;
    const int b = row / T_, t = row % T_;
    float* op = (t < S_) ? out + ((long long)b * S_ + t) * D_
                         : out + (long long)B_ * S_ * D_ + ((long long)b * E_ + (t - S_)) * D_;
#pragma unroll
    for (int i = 0; i < 3; i++) {
      const int c = tid + i * 256;
      op[c] = (v[i] - mean) * rs * b2f(g[c]) + b2f(beta[c]);
    }
  } else {
    u16* op = (u16*)out_ + (long long)row * D_;
#pragma unroll
    for (int i = 0; i < 3; i++) {
      const int c = tid + i * 256;
      op[c] = f2b((v[i] - mean) * rs * b2f(g[c]) + b2f(beta[c]));
    }
  }
}

__global__ __launch_bounds__(256) void transpose_kernel(
    const float* __restrict__ in, u16* __restrict__ out, int K, int N) {
  __shared__ u16 t[32][33];
  const int n0 = blockIdx.x * 32, k0 = blockIdx.y * 32;
  const int tx = threadIdx.x, ty = threadIdx.y;
#pragma unroll
  for (int i = 0; i < 4; i++)
    t[ty + i * 8][tx] = f2b(in[(long long)(k0 + ty + i * 8) * N + n0 + tx]);
  __syncthreads();
#pragma unroll
  for (int i = 0; i < 4; i++)
    out[(long long)(n0 + ty + i * 8) * K + k0 + tx] = t[tx][ty + i * 8];
}

struct T7 { const float* s[7]; u16* d[7]; };
__global__ __launch_bounds__(256) void transpose7_kernel(T7 a) {
  __shared__ u16 t[32][33];
  const float* in = a.s[blockIdx.z];
  u16* out = a.d[blockIdx.z];
  const int n0 = blockIdx.x * 32, k0 = blockIdx.y * 32;
  const int tx = threadIdx.x, ty = threadIdx.y;
#pragma unroll
  for (int i = 0; i < 4; i++)
    t[ty + i * 8][tx] = f2b(in[(long long)(k0 + ty + i * 8) * 768 + n0 + tx]);
  __syncthreads();
#pragma unroll
  for (int i = 0; i < 4; i++)
    out[(long long)(n0 + ty + i * 8) * 768 + k0 + tx] = t[tx][ty + i * 8];
}

__global__ __launch_bounds__(256) void concat_kernel(
    const float* __restrict__ w, const float* __restrict__ e, u16* __restrict__ x) {
  const long long i = (long long)(blockIdx.x * 256 + threadIdx.x) * 8;
  const long long NW = (long long)B_ * S_ * D_;
  const long long NE = (long long)B_ * E_ * D_;
  const long long SD = (long long)S_ * D_;
  const long long ED = (long long)E_ * D_;
  const long long TD = (long long)T_ * D_;
  const float* src;
  u16* dst;
  if (i < NW) {
    const long long b = i / SD, r = i % SD;
    src = w + i;
    dst = &x[b * TD + r];
  } else {
    const long long j = i - NW;
    if (j >= NE) return;
    const long long b = j / ED, r = j % ED;
    src = e + j;
    dst = &x[b * TD + SD + r];
  }
  const float4 f0 = *(const float4*)(src);
  const float4 f1 = *(const float4*)(src + 4);
  u16x8 o;
  o[0] = f2b(f0.x); o[1] = f2b(f0.y); o[2] = f2b(f0.z); o[3] = f2b(f0.w);
  o[4] = f2b(f1.x); o[5] = f2b(f1.y); o[6] = f2b(f1.z); o[7] = f2b(f1.w);
  *(u16x8*)dst = o;
}

struct CvtArgs { const float* src[13]; u16* dst[13]; int n[13]; };
__global__ __launch_bounds__(256) void cvt_vecs_kernel(CvtArgs a) {
  const int v = blockIdx.x;
  const float* s = a.src[v];
  u16* d = a.dst[v];
  const int n = a.n[v];
  for (int i = threadIdx.x; i < n; i += 256) d[i] = f2b(s[i]);
}

extern "C" void kernel_launch(void* const* d_in, const int* in_sizes, int n_in,
                              void* d_out, int out_size, void* d_ws, size_t ws_size,
                              hipStream_t stream) {
  (void)in_sizes; (void)n_in; (void)out_size; (void)ws_size;
  const float* word = (const float*)d_in[0];
  const float* ent = (const float*)d_in[1];
  const float* mask = (const float*)d_in[2];
  const float* W_q = (const float*)d_in[3];
  const float* b_q = (const float*)d_in[4];
  const float* W_k = (const float*)d_in[5];
  const float* b_k = (const float*)d_in[6];
  const float* W_v = (const float*)d_in[7];
  const float* b_v = (const float*)d_in[8];
  const float* W_w2e = (const float*)d_in[9];
  const float* b_w2e = (const float*)d_in[10];
  const float* W_e2w = (const float*)d_in[11];
  const float* b_e2w = (const float*)d_in[12];
  const float* W_e2e = (const float*)d_in[13];
  const float* b_e2e = (const float*)d_in[14];
  const float* W_ao = (const float*)d_in[15];
  const float* b_ao = (const float*)d_in[16];
  const float* g_ao = (const float*)d_in[17];
  const float* be_ao = (const float*)d_in[18];
  const float* W_i = (const float*)d_in[19];
  const float* b_i = (const float*)d_in[20];
  const float* W_o = (const float*)d_in[21];
  const float* b_o = (const float*)d_in[22];
  const float* g_o = (const float*)d_in[23];
  const float* be_o = (const float*)d_in[24];

  const size_t DD = (size_t)D_ * D_ * 2;
  const size_t DFF = (size_t)D_ * FF_ * 2;
  const size_t TD = (size_t)B_ * T_ * D_ * 2;
  size_t off = 0;
  char* base = (char*)d_ws;
  auto take = [&](size_t n) { void* p = base + off; off += n; return p; };
  u16* wqT = (u16*)take(DD);
  u16* wkT = (u16*)take(DD);
  u16* wvT = (u16*)take(DD);
  u16* ww2eT = (u16*)take(DD);
  u16* we2wT = (u16*)take(DD);
  u16* we2eT = (u16*)take(DD);
  u16* waoT = (u16*)take(DD);
  u16* wiT = (u16*)take(DFF);
  u16* woT = (u16*)take(DFF);
  u16* vecs = (u16*)take(2 * 16384);
  u16* xall = (u16*)take(TD);
  u16* qw = (u16*)take(TD);
  u16* qe = (u16*)take(TD);
  u16* kb = (u16*)take(TD);
  u16* vt = (u16*)take(TD);
  u16* ctxb = (u16*)take(TD);
  u16* inter = (u16*)take((size_t)B_ * T_ * FF_ * 2);
  u16* bq = vecs + 0 * 768;
  u16* bk = vecs + 1 * 768;
  u16* bv = vecs + 2 * 768;
  u16* bw2e = vecs + 3 * 768;
  u16* be2w = vecs + 4 * 768;
  u16* be2e = vecs + 5 * 768;
  u16* bao = vecs + 6 * 768;
  u16* gao = vecs + 7 * 768;
  u16* beao = vecs + 8 * 768;
  u16* bo = vecs + 9 * 768;
  u16* go = vecs + 10 * 768;
  u16* beo = vecs + 11 * 768;
  u16* bi = vecs + 12 * 768;  // 3072 elems
  u16* ao_raw = qw;
  u16* ao = kb;
  u16* out_raw = qe;

  CvtArgs ca;
  ca.src[0] = b_q;   ca.dst[0] = bq;   ca.n[0] = 768;
  ca.src[1] = b_k;   ca.dst[1] = bk;   ca.n[1] = 768;
  ca.src[2] = b_v;   ca.dst[2] = bv;   ca.n[2] = 768;
  ca.src[3] = b_w2e; ca.dst[3] = bw2e; ca.n[3] = 768;
  ca.src[4] = b_e2w; ca.dst[4] = be2w; ca.n[4] = 768;
  ca.src[5] = b_e2e; ca.dst[5] = be2e; ca.n[5] = 768;
  ca.src[6] = b_ao;  ca.dst[6] = bao;  ca.n[6] = 768;
  ca.src[7] = g_ao;  ca.dst[7] = gao;  ca.n[7] = 768;
  ca.src[8] = be_ao; ca.dst[8] = beao; ca.n[8] = 768;
  ca.src[9] = b_o;   ca.dst[9] = bo;   ca.n[9] = 768;
  ca.src[10] = g_o;  ca.dst[10] = go;  ca.n[10] = 768;
  ca.src[11] = be_o; ca.dst[11] = beo; ca.n[11] = 768;
  ca.src[12] = b_i;  ca.dst[12] = bi;  ca.n[12] = 3072;
  cvt_vecs_kernel<<<13, 256, 0, stream>>>(ca);

  T7 t7;
  t7.s[0] = W_q;   t7.d[0] = wqT;
  t7.s[1] = W_k;   t7.d[1] = wkT;
  t7.s[2] = W_v;   t7.d[2] = wvT;
  t7.s[3] = W_w2e; t7.d[3] = ww2eT;
  t7.s[4] = W_e2w; t7.d[4] = we2wT;
  t7.s[5] = W_e2e; t7.d[5] = we2eT;
  t7.s[6] = W_ao;  t7.d[6] = waoT;
  const dim3 tb(32, 8);
  transpose7_kernel<<<dim3(24, 24, 7), tb, 0, stream>>>(t7);
  transpose_kernel<<<dim3(96, 24), tb, 0, stream>>>(W_i, wiT, 768, 3072);
  transpose_kernel<<<dim3(24, 96), tb, 0, stream>>>(W_o, woT, 3072, 768);
  concat_kernel<<<3840, 256, 0, stream>>>(word, ent, xall);

  const long long TDs = (long long)T_ * D_;
  // merged K+V projection: y<6 -> kb (normal), y>=6 -> vt (transposed store)
  gemm_kernel<1, false><<<dim3(80, 12, 1), 256, 0, stream>>>(
      xall, wkT, wvT, nullptr, nullptr, bk, bv, nullptr, nullptr, kb, vt,
      768, 768, 768, 0, 0);
  // merged Q: y<6 -> qw (m<4: W_q, m=4: W_e2w), y>=6 -> qe (W_w2e / W_e2e)
  gemm_kernel<2, false><<<dim3(5, 12, 16), 256, 0, stream>>>(
      xall, wqT, we2wT, ww2eT, we2eT, bq, be2w, bw2e, be2e, qw, qe,
      768, 768, 768, TDs, TDs);

  attn_kernel<<<dim3(20, 12, 16), 256, 0, stream>>>(qw, qe, kb, vt, mask, ctxb);

  gemm_kernel<0, false><<<dim3(80, 6, 1), 256, 0, stream>>>(
      ctxb, waoT, nullptr, nullptr, nullptr, bao, nullptr, nullptr, nullptr,
      ao_raw, nullptr, 768, 768, 768, 0, 0);
  ln_kernel<0><<<10240, 256, 0, stream>>>(ao_raw, xall, gao, beao, ao);
  gemm_kernel<0, true><<<dim3(80, 24, 1), 256, 0, stream>>>(
      ao, wiT, nullptr, nullptr, nullptr, bi, nullptr, nullptr, nullptr,
      inter, nullptr, 768, 3072, 768, 0, 0);
  gemm_kernel<0, false><<<dim3(80, 6, 1), 256, 0, stream>>>(
      inter, woT, nullptr, nullptr, nullptr, bo, nullptr, nullptr, nullptr,
      out_raw, nullptr, 3072, 768, 3072, 0, 0);
  ln_kernel<1><<<10240, 256, 0, stream>>>(out_raw, ao, go, beo, d_out);
}

// Round 5
// 509.381 us; speedup vs baseline: 1.2999x; 1.0015x over previous
//
#include <hip/hip_runtime.h>
#include <stdint.h>

// ============================================================================
// LUKE entity-aware attention block, MI355X gfx950, round 4.
// FP32 I/O, bf16 MFMA internals. Round-4 change: XCD-aware block swizzle in
// attention (all 20 q-tiles of a (b,h) pair share an id%8 class -> per-XCD
// K/V working set ~3.8MB fits the 4MB L2). GEMM/LN/prep unchanged from r3.
// ============================================================================

#define B_ 16
#define S_ 512
#define E_ 128
#define T_ 640
#define D_ 768
#define H_ 12
#define DH_ 64
#define FF_ 3072
#define SCP_LD 664

typedef unsigned short u16;
typedef __bf16 bf16x8 __attribute__((ext_vector_type(8)));
typedef u16 u16x8 __attribute__((ext_vector_type(8)));
typedef u16 u16x4 __attribute__((ext_vector_type(4)));
typedef float f32x4 __attribute__((ext_vector_type(4)));

__device__ __forceinline__ float b2f(u16 v) {
  unsigned u = ((unsigned)v) << 16;
  return __builtin_bit_cast(float, u);
}
__device__ __forceinline__ u16 f2b(float f) {  // RNE
  unsigned u = __builtin_bit_cast(unsigned, f);
  u += 0x7FFFu + ((u >> 16) & 1u);
  return (u16)(u >> 16);
}

__device__ __forceinline__ void gl_lds16(const u16* g, u16* l) {
  __builtin_amdgcn_global_load_lds((__attribute__((address_space(1))) const void*)g,
                                   (__attribute__((address_space(3))) void*)l, 16, 0, 0);
}

// ============================================================================
// GEMM core: 128x128 tile, BK=64 as two BK=32 panels, 4 waves, 32 MFMA per
// barrier-pair.
// ============================================================================
__device__ __forceinline__ void gemm_core(
    const u16* __restrict__ A, const u16* __restrict__ Bt, int lda, int K,
    u16* As, u16* Bs, f32x4 (&acc)[4][4]) {
  const int tid = threadIdx.x;
  const int lane = tid & 63, wave = tid >> 6;
  const int wm = (wave & 1) << 6, wn = (wave >> 1) << 6;
  const int l15 = lane & 15, quad = lane >> 4;

  const int r0 = tid >> 2, c0 = (tid & 3) << 3;
  const u16* ga0 = A + (long long)r0 * lda + c0;
  const u16* ga1 = A + (long long)(r0 + 64) * lda + c0;
  const u16* gb0 = Bt + (long long)r0 * K + c0;
  const u16* gb1 = Bt + (long long)(r0 + 64) * K + c0;

  for (int k0 = 0; k0 < K; k0 += 64) {
    __syncthreads();
    gl_lds16(ga0 + k0, &As[tid * 8]);
    gl_lds16(ga1 + k0, &As[2048 + tid * 8]);
    gl_lds16(ga0 + k0 + 32, &As[4096 + tid * 8]);
    gl_lds16(ga1 + k0 + 32, &As[6144 + tid * 8]);
    gl_lds16(gb0 + k0, &Bs[tid * 8]);
    gl_lds16(gb1 + k0, &Bs[2048 + tid * 8]);
    gl_lds16(gb0 + k0 + 32, &Bs[4096 + tid * 8]);
    gl_lds16(gb1 + k0 + 32, &Bs[6144 + tid * 8]);
    __syncthreads();

#pragma unroll
    for (int p = 0; p < 2; p++) {
      bf16x8 af[4], bfr[4];
#pragma unroll
      for (int i = 0; i < 4; i++)
        af[i] = *(const bf16x8*)&As[p * 4096 + (wm + i * 16 + l15) * 32 + quad * 8];
#pragma unroll
      for (int i = 0; i < 4; i++)
        bfr[i] = *(const bf16x8*)&Bs[p * 4096 + (wn + i * 16 + l15) * 32 + quad * 8];
#pragma unroll
      for (int i = 0; i < 4; i++)
#pragma unroll
        for (int j = 0; j < 4; j++)
          acc[i][j] = __builtin_amdgcn_mfma_f32_16x16x32_bf16(af[i], bfr[j], acc[i][j], 0, 0, 0);
    }
  }
}

__device__ __forceinline__ void epi_store(
    f32x4 (&acc)[4][4], const u16* __restrict__ bias, u16* __restrict__ C,
    int m0, int n0, int ldc, bool gelu) {
  const int tid = threadIdx.x;
  const int lane = tid & 63, wave = tid >> 6;
  const int wm = (wave & 1) << 6, wn = (wave >> 1) << 6;
  const int l15 = lane & 15, quad = lane >> 4;
  float bv[4];
#pragma unroll
  for (int j = 0; j < 4; j++) bv[j] = b2f(bias[n0 + wn + j * 16 + l15]);
#pragma unroll
  for (int i = 0; i < 4; i++) {
    const int row = m0 + wm + i * 16 + quad * 4;
#pragma unroll
    for (int j = 0; j < 4; j++) {
      const int col = n0 + wn + j * 16 + l15;
#pragma unroll
      for (int r = 0; r < 4; r++) {
        float v = acc[i][j][r] + bv[j];
        if (gelu) v = 0.5f * v * (1.0f + erff(v * 0.70710678118654752f));
        C[(long long)(row + r) * ldc + col] = f2b(v);
      }
    }
  }
}

// MODE 0: plain C = A@Bt^T + bias ; MODE 1: merged KV ; MODE 2: merged Q
template <int MODE, bool GELU>
__global__ __launch_bounds__(256) void gemm_kernel(
    const u16* __restrict__ A, const u16* __restrict__ Bt0,
    const u16* __restrict__ Bt1, const u16* __restrict__ Bt2,
    const u16* __restrict__ Bt3, const u16* __restrict__ bias0,
    const u16* __restrict__ bias1, const u16* __restrict__ bias2,
    const u16* __restrict__ bias3, u16* __restrict__ C0, u16* __restrict__ C1,
    int lda, int ldc, int K, long long sA, long long sC) {
  __shared__ __align__(16) u16 As[8192];
  __shared__ __align__(16) u16 Bs[8192];

  const int m0 = blockIdx.x * 128;
  int n0;
  const u16 *Bt, *bias;
  u16* C;
  bool vstore = false;
  if (MODE == 0) {
    n0 = blockIdx.y * 128;
    Bt = Bt0; bias = bias0; C = C0;
  } else if (MODE == 1) {
    if (blockIdx.y < 6) { n0 = blockIdx.y * 128; Bt = Bt0; bias = bias0; C = C0; }
    else { n0 = (blockIdx.y - 6) * 128; Bt = Bt1; bias = bias1; C = C1; vstore = true; }
  } else {
    const bool isE = (blockIdx.x >= 4);
    if (blockIdx.y < 6) {
      n0 = blockIdx.y * 128;
      Bt = isE ? Bt1 : Bt0; bias = isE ? bias1 : bias0; C = C0;
    } else {
      n0 = (blockIdx.y - 6) * 128;
      Bt = isE ? Bt3 : Bt2; bias = isE ? bias3 : bias2; C = C1;
    }
  }

  const u16* Ab = A + (long long)blockIdx.z * sA + (long long)m0 * lda;
  C += (long long)blockIdx.z * sC;

  f32x4 acc[4][4] = {};
  gemm_core(Ab, Bt + (long long)n0 * K, lda, K, As, Bs, acc);

  if (MODE == 1 && vstore) {
    const int tid = threadIdx.x;
    const int lane = tid & 63, wave = tid >> 6;
    const int wm = (wave & 1) << 6, wn = (wave >> 1) << 6;
    const int l15 = lane & 15, quad = lane >> 4;
    float bv[4];
#pragma unroll
    for (int j = 0; j < 4; j++) bv[j] = b2f(bias[n0 + wn + j * 16 + l15]);
#pragma unroll
    for (int i = 0; i < 4; i++) {
      const int grow = m0 + wm + i * 16 + quad * 4;
      const int bb = grow / T_, tt = grow - bb * T_;
#pragma unroll
      for (int j = 0; j < 4; j++) {
        const int col = n0 + wn + j * 16 + l15;
        u16x4 pk;
#pragma unroll
        for (int r = 0; r < 4; r++) pk[r] = f2b(acc[i][j][r] + bv[j]);
        *(u16x4*)&C[(((long long)bb * H_ + (col >> 6)) * DH_ + (col & 63)) * T_ + tt] = pk;
      }
    }
  } else {
    epi_store(acc, bias, C, m0, n0, ldc, GELU);
  }
}

// ============================================================================
// Fused attention v3: 1D grid 3840, XCD-aware swizzle. id&7 picks the XCD
// class; each class owns 24 (b,h) pairs entirely (20 q-tiles each), walked
// consecutively -> per-XCD K/V working set ~3.8MB fits 4MB L2.
// ============================================================================
__global__ __launch_bounds__(256) void attn_kernel(
    const u16* __restrict__ Qw, const u16* __restrict__ Qe,
    const u16* __restrict__ Kb, const u16* __restrict__ Vt,
    const float* __restrict__ mask, u16* __restrict__ ctx) {
  const int id = blockIdx.x;
  const int xcd = id & 7;
  const int slot = id >> 3;          // 0..479
  const int pl = slot / 20;          // 0..23 pair-local
  const int qt = slot - pl * 20;     // 0..19
  const int pair = xcd * 24 + pl;    // 0..191
  const int b = pair / H_, h = pair - b * H_;
  const int q0 = qt * 32;

  __shared__ __align__(16) u16 scp[32 * SCP_LD];
  __shared__ float rsum[32];

  const int tid = threadIdx.x;
  const int lane = tid & 63, wave = tid >> 6;
  const int l15 = lane & 15, quad = lane >> 4;

  const long long bh = (long long)b * T_ * D_ + h * DH_;
  const long long bhV = ((long long)b * H_ + h) * DH_ * T_;

  bf16x8 qf[2][2][2];
#pragma unroll
  for (int g = 0; g < 2; g++) {
    const u16* qwp = Qw + bh + (long long)(q0 + g * 16 + l15) * D_ + quad * 8;
    const u16* qep = Qe + bh + (long long)(q0 + g * 16 + l15) * D_ + quad * 8;
    qf[g][0][0] = *(const bf16x8*)(qwp);
    qf[g][0][1] = *(const bf16x8*)(qwp + 32);
    qf[g][1][0] = *(const bf16x8*)(qep);
    qf[g][1][1] = *(const bf16x8*)(qep + 32);
  }

#pragma unroll
  for (int i = 0; i < 10; i++) {
    const int key0 = wave * 160 + i * 16;
    const u16* kp = Kb + bh + (long long)(key0 + l15) * D_ + quad * 8;
    const bf16x8 kf0 = *(const bf16x8*)(kp);
    const bf16x8 kf1 = *(const bf16x8*)(kp + 32);
    const float mv = mask[b * T_ + key0 + l15];
    const int e = (key0 < S_) ? 0 : 1;
#pragma unroll
    for (int g = 0; g < 2; g++) {
      f32x4 a = {0.f, 0.f, 0.f, 0.f};
      a = __builtin_amdgcn_mfma_f32_16x16x32_bf16(qf[g][e][0], kf0, a, 0, 0, 0);
      a = __builtin_amdgcn_mfma_f32_16x16x32_bf16(qf[g][e][1], kf1, a, 0, 0, 0);
#pragma unroll
      for (int r = 0; r < 4; r++)
        scp[(g * 16 + quad * 4 + r) * SCP_LD + key0 + l15] = f2b(a[r] * 0.125f + mv);
    }
  }
  __syncthreads();

  {
    const int row = tid >> 3, ck = tid & 7;
    float mx = -1e30f;
#pragma unroll
    for (int c = 0; c < 10; c++) {
      const u16x8 v = *(const u16x8*)&scp[row * SCP_LD + c * 64 + ck * 8];
#pragma unroll
      for (int e = 0; e < 8; e++) mx = fmaxf(mx, b2f(v[e]));
    }
#pragma unroll
    for (int d = 4; d; d >>= 1) mx = fmaxf(mx, __shfl_xor(mx, d, 8));
    float sum = 0.f;
#pragma unroll
    for (int c = 0; c < 10; c++) {
      u16* p = &scp[row * SCP_LD + c * 64 + ck * 8];
      const u16x8 v = *(const u16x8*)p;
      u16x8 o;
#pragma unroll
      for (int e = 0; e < 8; e++) {
        const float ex = __expf(b2f(v[e]) - mx);
        sum += ex;
        o[e] = f2b(ex);
      }
      *(u16x8*)p = o;
    }
#pragma unroll
    for (int d = 4; d; d >>= 1) sum += __shfl_xor(sum, d, 8);
    if (ck == 0) rsum[row] = sum;
  }
  __syncthreads();

  f32x4 o0 = {0.f, 0.f, 0.f, 0.f}, o1 = {0.f, 0.f, 0.f, 0.f};
  const u16* vrow = Vt + bhV + (long long)(wave * 16 + l15) * T_;
#pragma unroll
  for (int kc = 0; kc < T_; kc += 64) {
#pragma unroll
    for (int ks = 0; ks < 2; ks++) {
      const int ko = kc + ks * 32 + quad * 8;
      const bf16x8 vf = *(const bf16x8*)(vrow + ko);
      const bf16x8 p0 = *(const bf16x8*)&scp[l15 * SCP_LD + ko];
      const bf16x8 p1 = *(const bf16x8*)&scp[(16 + l15) * SCP_LD + ko];
      o0 = __builtin_amdgcn_mfma_f32_16x16x32_bf16(p0, vf, o0, 0, 0, 0);
      o1 = __builtin_amdgcn_mfma_f32_16x16x32_bf16(p1, vf, o1, 0, 0, 0);
    }
  }

  u16* cp0 = ctx + bh + (long long)(q0 + quad * 4) * D_ + wave * 16 + l15;
#pragma unroll
  for (int r = 0; r < 4; r++) cp0[(long long)r * D_] = f2b(o0[r] / rsum[quad * 4 + r]);
  u16* cp1 = ctx + bh + (long long)(q0 + 16 + quad * 4) * D_ + wave * 16 + l15;
#pragma unroll
  for (int r = 0; r < 4; r++) cp1[(long long)r * D_] = f2b(o1[r] / rsum[16 + quad * 4 + r]);
}

// ============================================================================
// LayerNorm over D=768 with fused residual add.
// ============================================================================
template <int SPLIT>
__global__ __launch_bounds__(256) void ln_kernel(
    const u16* __restrict__ x, const u16* __restrict__ res,
    const u16* __restrict__ g, const u16* __restrict__ beta,
    void* __restrict__ out_) {
  const int row = blockIdx.x;
  const int tid = threadIdx.x;
  const u16* xp = x + (long long)row * D_;
  const u16* rp = res + (long long)row * D_;
  float v[3], s = 0.f, s2 = 0.f;
#pragma unroll
  for (int i = 0; i < 3; i++) {
    const int c = tid + i * 256;
    v[i] = b2f(xp[c]) + b2f(rp[c]);
    s += v[i];
    s2 += v[i] * v[i];
  }
#pragma unroll
  for (int d = 32; d; d >>= 1) {
    s += __shfl_xor(s, d, 64);
    s2 += __shfl_xor(s2, d, 64);
  }
  __shared__ float red[8];
  const int wave = tid >> 6;
  if ((tid & 63) == 0) { red[wave * 2] = s; red[wave * 2 + 1] = s2; }
  __syncthreads();
  s = red[0] + red[2] + red[4] + red[6];
  s2 = red[1] + red[3] + red[5] + red[7];
  const float mean = s * (1.f / 768.f);
  const float var = s2 * (1.f / 768.f) - mean * mean;
  const float rs = rsqrtf(var + 1e-12f);
  if (SPLIT) {
    float* out = (float*)out_;
    const int b = row / T_, t = row % T_;
    float* op = (t < S_) ? out + ((long long)b * S_ + t) * D_
                         : out + (long long)B_ * S_ * D_ + ((long long)b * E_ + (t - S_)) * D_;
#pragma unroll
    for (int i = 0; i < 3; i++) {
      const int c = tid + i * 256;
      op[c] = (v[i] - mean) * rs * b2f(g[c]) + b2f(beta[c]);
    }
  } else {
    u16* op = (u16*)out_ + (long long)row * D_;
#pragma unroll
    for (int i = 0; i < 3; i++) {
      const int c = tid + i * 256;
      op[c] = f2b((v[i] - mean) * rs * b2f(g[c]) + b2f(beta[c]));
    }
  }
}

__global__ __launch_bounds__(256) void transpose_kernel(
    const float* __restrict__ in, u16* __restrict__ out, int K, int N) {
  __shared__ u16 t[32][33];
  const int n0 = blockIdx.x * 32, k0 = blockIdx.y * 32;
  const int tx = threadIdx.x, ty = threadIdx.y;
#pragma unroll
  for (int i = 0; i < 4; i++)
    t[ty + i * 8][tx] = f2b(in[(long long)(k0 + ty + i * 8) * N + n0 + tx]);
  __syncthreads();
#pragma unroll
  for (int i = 0; i < 4; i++)
    out[(long long)(n0 + ty + i * 8) * K + k0 + tx] = t[tx][ty + i * 8];
}

struct T7 { const float* s[7]; u16* d[7]; };
__global__ __launch_bounds__(256) void transpose7_kernel(T7 a) {
  __shared__ u16 t[32][33];
  const float* in = a.s[blockIdx.z];
  u16* out = a.d[blockIdx.z];
  const int n0 = blockIdx.x * 32, k0 = blockIdx.y * 32;
  const int tx = threadIdx.x, ty = threadIdx.y;
#pragma unroll
  for (int i = 0; i < 4; i++)
    t[ty + i * 8][tx] = f2b(in[(long long)(k0 + ty + i * 8) * 768 + n0 + tx]);
  __syncthreads();
#pragma unroll
  for (int i = 0; i < 4; i++)
    out[(long long)(n0 + ty + i * 8) * 768 + k0 + tx] = t[tx][ty + i * 8];
}

__global__ __launch_bounds__(256) void concat_kernel(
    const float* __restrict__ w, const float* __restrict__ e, u16* __restrict__ x) {
  const long long i = (long long)(blockIdx.x * 256 + threadIdx.x) * 8;
  const long long NW = (long long)B_ * S_ * D_;
  const long long NE = (long long)B_ * E_ * D_;
  const long long SD = (long long)S_ * D_;
  const long long ED = (long long)E_ * D_;
  const long long TD = (long long)T_ * D_;
  const float* src;
  u16* dst;
  if (i < NW) {
    const long long b = i / SD, r = i % SD;
    src = w + i;
    dst = &x[b * TD + r];
  } else {
    const long long j = i - NW;
    if (j >= NE) return;
    const long long b = j / ED, r = j % ED;
    src = e + j;
    dst = &x[b * TD + SD + r];
  }
  const float4 f0 = *(const float4*)(src);
  const float4 f1 = *(const float4*)(src + 4);
  u16x8 o;
  o[0] = f2b(f0.x); o[1] = f2b(f0.y); o[2] = f2b(f0.z); o[3] = f2b(f0.w);
  o[4] = f2b(f1.x); o[5] = f2b(f1.y); o[6] = f2b(f1.z); o[7] = f2b(f1.w);
  *(u16x8*)dst = o;
}

struct CvtArgs { const float* src[13]; u16* dst[13]; int n[13]; };
__global__ __launch_bounds__(256) void cvt_vecs_kernel(CvtArgs a) {
  const int v = blockIdx.x;
  const float* s = a.src[v];
  u16* d = a.dst[v];
  const int n = a.n[v];
  for (int i = threadIdx.x; i < n; i += 256) d[i] = f2b(s[i]);
}

extern "C" void kernel_launch(void* const* d_in, const int* in_sizes, int n_in,
                              void* d_out, int out_size, void* d_ws, size_t ws_size,
                              hipStream_t stream) {
  (void)in_sizes; (void)n_in; (void)out_size; (void)ws_size;
  const float* word = (const float*)d_in[0];
  const float* ent = (const float*)d_in[1];
  const float* mask = (const float*)d_in[2];
  const float* W_q = (const float*)d_in[3];
  const float* b_q = (const float*)d_in[4];
  const float* W_k = (const float*)d_in[5];
  const float* b_k = (const float*)d_in[6];
  const float* W_v = (const float*)d_in[7];
  const float* b_v = (const float*)d_in[8];
  const float* W_w2e = (const float*)d_in[9];
  const float* b_w2e = (const float*)d_in[10];
  const float* W_e2w = (const float*)d_in[11];
  const float* b_e2w = (const float*)d_in[12];
  const float* W_e2e = (const float*)d_in[13];
  const float* b_e2e = (const float*)d_in[14];
  const float* W_ao = (const float*)d_in[15];
  const float* b_ao = (const float*)d_in[16];
  const float* g_ao = (const float*)d_in[17];
  const float* be_ao = (const float*)d_in[18];
  const float* W_i = (const float*)d_in[19];
  const float* b_i = (const float*)d_in[20];
  const float* W_o = (const float*)d_in[21];
  const float* b_o = (const float*)d_in[22];
  const float* g_o = (const float*)d_in[23];
  const float* be_o = (const float*)d_in[24];

  const size_t DD = (size_t)D_ * D_ * 2;
  const size_t DFF = (size_t)D_ * FF_ * 2;
  const size_t TD = (size_t)B_ * T_ * D_ * 2;
  size_t off = 0;
  char* base = (char*)d_ws;
  auto take = [&](size_t n) { void* p = base + off; off += n; return p; };
  u16* wqT = (u16*)take(DD);
  u16* wkT = (u16*)take(DD);
  u16* wvT = (u16*)take(DD);
  u16* ww2eT = (u16*)take(DD);
  u16* we2wT = (u16*)take(DD);
  u16* we2eT = (u16*)take(DD);
  u16* waoT = (u16*)take(DD);
  u16* wiT = (u16*)take(DFF);
  u16* woT = (u16*)take(DFF);
  u16* vecs = (u16*)take(2 * 16384);
  u16* xall = (u16*)take(TD);
  u16* qw = (u16*)take(TD);
  u16* qe = (u16*)take(TD);
  u16* kb = (u16*)take(TD);
  u16* vt = (u16*)take(TD);
  u16* ctxb = (u16*)take(TD);
  u16* inter = (u16*)take((size_t)B_ * T_ * FF_ * 2);
  u16* bq = vecs + 0 * 768;
  u16* bk = vecs + 1 * 768;
  u16* bv = vecs + 2 * 768;
  u16* bw2e = vecs + 3 * 768;
  u16* be2w = vecs + 4 * 768;
  u16* be2e = vecs + 5 * 768;
  u16* bao = vecs + 6 * 768;
  u16* gao = vecs + 7 * 768;
  u16* beao = vecs + 8 * 768;
  u16* bo = vecs + 9 * 768;
  u16* go = vecs + 10 * 768;
  u16* beo = vecs + 11 * 768;
  u16* bi = vecs + 12 * 768;  // 3072 elems
  u16* ao_raw = qw;
  u16* ao = kb;
  u16* out_raw = qe;

  CvtArgs ca;
  ca.src[0] = b_q;   ca.dst[0] = bq;   ca.n[0] = 768;
  ca.src[1] = b_k;   ca.dst[1] = bk;   ca.n[1] = 768;
  ca.src[2] = b_v;   ca.dst[2] = bv;   ca.n[2] = 768;
  ca.src[3] = b_w2e; ca.dst[3] = bw2e; ca.n[3] = 768;
  ca.src[4] = b_e2w; ca.dst[4] = be2w; ca.n[4] = 768;
  ca.src[5] = b_e2e; ca.dst[5] = be2e; ca.n[5] = 768;
  ca.src[6] = b_ao;  ca.dst[6] = bao;  ca.n[6] = 768;
  ca.src[7] = g_ao;  ca.dst[7] = gao;  ca.n[7] = 768;
  ca.src[8] = be_ao; ca.dst[8] = beao; ca.n[8] = 768;
  ca.src[9] = b_o;   ca.dst[9] = bo;   ca.n[9] = 768;
  ca.src[10] = g_o;  ca.dst[10] = go;  ca.n[10] = 768;
  ca.src[11] = be_o; ca.dst[11] = beo; ca.n[11] = 768;
  ca.src[12] = b_i;  ca.dst[12] = bi;  ca.n[12] = 3072;
  cvt_vecs_kernel<<<13, 256, 0, stream>>>(ca);

  T7 t7;
  t7.s[0] = W_q;   t7.d[0] = wqT;
  t7.s[1] = W_k;   t7.d[1] = wkT;
  t7.s[2] = W_v;   t7.d[2] = wvT;
  t7.s[3] = W_w2e; t7.d[3] = ww2eT;
  t7.s[4] = W_e2w; t7.d[4] = we2wT;
  t7.s[5] = W_e2e; t7.d[5] = we2eT;
  t7.s[6] = W_ao;  t7.d[6] = waoT;
  const dim3 tb(32, 8);
  transpose7_kernel<<<dim3(24, 24, 7), tb, 0, stream>>>(t7);
  transpose_kernel<<<dim3(96, 24), tb, 0, stream>>>(W_i, wiT, 768, 3072);
  transpose_kernel<<<dim3(24, 96), tb, 0, stream>>>(W_o, woT, 3072, 768);
  concat_kernel<<<3840, 256, 0, stream>>>(word, ent, xall);

  const long long TDs = (long long)T_ * D_;
  gemm_kernel<1, false><<<dim3(80, 12, 1), 256, 0, stream>>>(
      xall, wkT, wvT, nullptr, nullptr, bk, bv, nullptr, nullptr, kb, vt,
      768, 768, 768, 0, 0);
  gemm_kernel<2, false><<<dim3(5, 12, 16), 256, 0, stream>>>(
      xall, wqT, we2wT, ww2eT, we2eT, bq, be2w, bw2e, be2e, qw, qe,
      768, 768, 768, TDs, TDs);

  attn_kernel<<<3840, 256, 0, stream>>>(qw, qe, kb, vt, mask, ctxb);

  gemm_kernel<0, false><<<dim3(80, 6, 1), 256, 0, stream>>>(
      ctxb, waoT, nullptr, nullptr, nullptr, bao, nullptr, nullptr, nullptr,
      ao_raw, nullptr, 768, 768, 768, 0, 0);
  ln_kernel<0><<<10240, 256, 0, stream>>>(ao_raw, xall, gao, beao, ao);
  gemm_kernel<0, true><<<dim3(80, 24, 1), 256, 0, stream>>>(
      ao, wiT, nullptr, nullptr, nullptr, bi, nullptr, nullptr, nullptr,
      inter, nullptr, 768, 3072, 768, 0, 0);
  gemm_kernel<0, false><<<dim3(80, 6, 1), 256, 0, stream>>>(
      inter, woT, nullptr, nullptr, nullptr, bo, nullptr, nullptr, nullptr,
      out_raw, nullptr, 3072, 768, 3072, 0, 0);
  ln_kernel<1><<<10240, 256, 0, stream>>>(out_raw, ao, go, beo, d_out);
}